// Round 2
// baseline (5993.859 us; speedup 1.0000x reference)
//
#include <hip/hip_runtime.h>
#include <hip/hip_bf16.h>

// GPT-2 small forward on gfx950. bf16 MFMA GEMMs (f32 accum), flash attention.
// R2: lm_head uses 256x128 tile (halves B re-reads) + nontemporal C stores
//     (stop 823MB f32 output from thrashing embT out of L3);
//     proj/fc2 use split-K (occupancy: 192 -> 384/768 blocks) + fused reduce.

typedef __bf16 bh_t;
typedef __bf16 bfx4 __attribute__((ext_vector_type(4)));
typedef __bf16 bfx8 __attribute__((ext_vector_type(8)));
typedef float  fx4  __attribute__((ext_vector_type(4)));

#define CDIM 768
#define TSEQ 1024
#define NHEAD 12
#define HDIM 64
#define NLAYER 12
#define MROWS 4096          // B*T
#define VOCAB 50257
#define VPAD  50304         // 393 * 128

__device__ __forceinline__ void gload_lds16(const void* g, void* l) {
  __builtin_amdgcn_global_load_lds(
      (const __attribute__((address_space(1))) void*)g,
      (__attribute__((address_space(3))) void*)l, 16, 0, 0);
}

__device__ __forceinline__ fx4 mfma16(bfx8 a, bfx8 b, fx4 c) {
  return __builtin_amdgcn_mfma_f32_16x16x32_bf16(a, b, c, 0, 0, 0);
}

// ---------------------------------------------------------------------------
// GEMM: C[M,N] = A[M,K] @ B^T[N,K]  (+bias, +gelu, +residual), out f32 or bf16
// 128x128 tile, BK=32, 4 waves (2x2). lda = row stride of A and B (>= K).
// flags: 1=bias, 2=residual(f32, ld=N), 4=gelu, 8=out bf16. flags=0 -> raw f32.
// ---------------------------------------------------------------------------
__global__ __launch_bounds__(256, 3) void gemm_bt(
    const bh_t* __restrict__ A, const bh_t* __restrict__ B,
    const float* __restrict__ bias, const float* __restrict__ resid,
    void* __restrict__ outp, int M, int N, int K, int lda, int flags)
{
  __shared__ bh_t As[4][128][8];   // [k-block][row][8 contiguous k]
  __shared__ bh_t Bs[4][128][8];
  const int tid  = threadIdx.x;
  const int wave = tid >> 6, lane = tid & 63;
  const int g = lane >> 4, r16 = lane & 15;
  const int m0 = blockIdx.x * 128, n0 = blockIdx.y * 128;
  const int wm = (wave >> 1) * 64, wn = (wave & 1) * 64;

  fx4 acc[4][4] = {};

  const int c0 = tid, c1 = tid + 256;
  const int row0 = c0 & 127, kb0 = c0 >> 7;
  const int row1 = c1 & 127, kb1 = c1 >> 7;
  bh_t* AsF = &As[0][0][0];
  bh_t* BsF = &Bs[0][0][0];

  for (int k0 = 0; k0 < K; k0 += 32) {
    gload_lds16(A + (size_t)(m0 + row0) * lda + k0 + kb0 * 8, AsF + (size_t)(wave * 64) * 8);
    gload_lds16(A + (size_t)(m0 + row1) * lda + k0 + kb1 * 8, AsF + (size_t)(256 + wave * 64) * 8);
    gload_lds16(B + (size_t)(n0 + row0) * lda + k0 + kb0 * 8, BsF + (size_t)(wave * 64) * 8);
    gload_lds16(B + (size_t)(n0 + row1) * lda + k0 + kb1 * 8, BsF + (size_t)(256 + wave * 64) * 8);
    __syncthreads();   // drains vmcnt -> LDS tiles ready
    bfx8 af[4], bfr[4];
    #pragma unroll
    for (int mi = 0; mi < 4; ++mi) af[mi]  = *(const bfx8*)&As[g][wm + mi * 16 + r16][0];
    #pragma unroll
    for (int ni = 0; ni < 4; ++ni) bfr[ni] = *(const bfx8*)&Bs[g][wn + ni * 16 + r16][0];
    #pragma unroll
    for (int mi = 0; mi < 4; ++mi)
      #pragma unroll
      for (int ni = 0; ni < 4; ++ni)
        acc[mi][ni] = mfma16(af[mi], bfr[ni], acc[mi][ni]);
    __syncthreads();   // all reads done before next stage overwrites
  }

  const bool hasBias = flags & 1, hasRes = flags & 2;
  const bool doGelu  = flags & 4, outBf  = flags & 8;
  float* outF = (float*)outp;
  bh_t*  outB = (bh_t*)outp;
  #pragma unroll
  for (int mi = 0; mi < 4; ++mi) {
    #pragma unroll
    for (int ni = 0; ni < 4; ++ni) {
      const int col = n0 + wn + ni * 16 + r16;
      if (col >= N) continue;
      const int rowb = m0 + wm + mi * 16 + 4 * g;
      const float bv = hasBias ? bias[col] : 0.0f;
      #pragma unroll
      for (int rr = 0; rr < 4; ++rr) {
        const size_t idx = (size_t)(rowb + rr) * N + col;
        float v = acc[mi][ni][rr] + bv;
        if (doGelu) v = 0.5f * v * (1.0f + erff(v * 0.70710678118654752f));
        if (hasRes) v += resid[idx];
        if (outBf) outB[idx] = (bh_t)v; else outF[idx] = v;
      }
    }
  }
}

// ---------------------------------------------------------------------------
// lm_head GEMM: 256x128 tile, BK=32, 8 waves (4Mx2N), 512 threads.
// Nontemporal f32 stores (keep embT resident in L3). No post-ops.
// grid = (M/256, N'/128) with B padded to N' rows.
// ---------------------------------------------------------------------------
__global__ __launch_bounds__(512, 4) void gemm_lm(
    const bh_t* __restrict__ A, const bh_t* __restrict__ B,
    float* __restrict__ outF, int M, int N, int K)
{
  __shared__ bh_t As[4][256][8];
  __shared__ bh_t Bs[4][128][8];
  const int tid  = threadIdx.x;
  const int wave = tid >> 6, lane = tid & 63;
  const int g = lane >> 4, r16 = lane & 15;
  const int m0 = blockIdx.x * 256, n0 = blockIdx.y * 128;
  const int wm = (wave >> 1) * 64, wn = (wave & 1) * 64;

  fx4 acc[4][4] = {};

  const int rowA = tid & 255, kbA = tid >> 8;       // + (tid+512): kbA+2
  const int rowB = tid & 127, kbB = tid >> 7;
  bh_t* AsF = &As[0][0][0];
  bh_t* BsF = &Bs[0][0][0];

  for (int k0 = 0; k0 < K; k0 += 32) {
    gload_lds16(A + (size_t)(m0 + rowA) * K + k0 + kbA * 8,       AsF + (size_t)(wave * 64) * 8);
    gload_lds16(A + (size_t)(m0 + rowA) * K + k0 + (kbA + 2) * 8, AsF + (size_t)(512 + wave * 64) * 8);
    gload_lds16(B + (size_t)(n0 + rowB) * K + k0 + kbB * 8,       BsF + (size_t)(wave * 64) * 8);
    __syncthreads();
    bfx8 af[4], bfr[4];
    #pragma unroll
    for (int mi = 0; mi < 4; ++mi) af[mi]  = *(const bfx8*)&As[g][wm + mi * 16 + r16][0];
    #pragma unroll
    for (int ni = 0; ni < 4; ++ni) bfr[ni] = *(const bfx8*)&Bs[g][wn + ni * 16 + r16][0];
    #pragma unroll
    for (int mi = 0; mi < 4; ++mi)
      #pragma unroll
      for (int ni = 0; ni < 4; ++ni)
        acc[mi][ni] = mfma16(af[mi], bfr[ni], acc[mi][ni]);
    __syncthreads();
  }

  #pragma unroll
  for (int mi = 0; mi < 4; ++mi) {
    #pragma unroll
    for (int ni = 0; ni < 4; ++ni) {
      const int col = n0 + wn + ni * 16 + r16;
      if (col >= N) continue;
      const int rowb = m0 + wm + mi * 16 + 4 * g;
      #pragma unroll
      for (int rr = 0; rr < 4; ++rr) {
        const size_t idx = (size_t)(rowb + rr) * N + col;
        __builtin_nontemporal_store(acc[mi][ni][rr], &outF[idx]);
      }
    }
  }
}

// ---------------------------------------------------------------------------
// split-K reduce: x[idx] = resid[idx] + bias[col] + sum_s part[s][idx]
// N multiple of 4; in-place on x (resid == out).
// ---------------------------------------------------------------------------
__global__ __launch_bounds__(256) void sk_reduce(
    const float* __restrict__ part, const float* __restrict__ bias,
    float* __restrict__ x, int N, int S)
{
  const size_t i4 = ((size_t)blockIdx.x * 256 + threadIdx.x) * 4;
  const size_t stride = (size_t)MROWS * N;
  float4 a = *(const float4*)(part + i4);
  for (int s = 1; s < S; ++s) {
    const float4 p = *(const float4*)(part + s * stride + i4);
    a.x += p.x; a.y += p.y; a.z += p.z; a.w += p.w;
  }
  const int col = (int)(i4 % N);
  const float4 bv = *(const float4*)(bias + col);
  const float4 rv = *(const float4*)(x + i4);
  a.x += bv.x + rv.x; a.y += bv.y + rv.y; a.z += bv.z + rv.z; a.w += bv.w + rv.w;
  *(float4*)(x + i4) = a;
}

// ---------------------------------------------------------------------------
// Flash attention, causal. One wave per (b, h, 16 q-rows).
// ---------------------------------------------------------------------------
__global__ __launch_bounds__(256) void attn_fwd(
    const bh_t* __restrict__ qkv, const bh_t* __restrict__ vT,
    bh_t* __restrict__ outb)
{
  __shared__ bh_t P[4][16][56];
  const int wave = threadIdx.x >> 6, lane = threadIdx.x & 63;
  const int g = lane >> 4, r16 = lane & 15;
  const int gw = blockIdx.x * 4 + wave;
  const int qblk = gw & 63;
  const int bh = gw >> 6;
  const int h = bh % NHEAD, b = bh / NHEAD;
  const int qbase = qblk * 16;
  const int qidx = qbase + r16;

  const bh_t* qp = qkv + (size_t)(b * TSEQ + qbase + r16) * (3 * CDIM) + h * HDIM + 8 * g;
  const bfx8 qf0 = *(const bfx8*)qp;
  const bfx8 qf1 = *(const bfx8*)(qp + 32);

  fx4 o[4] = {};
  float m = -INFINITY, l = 0.0f;
  const int ntiles = qblk / 2 + 1;

  for (int t = 0; t < ntiles; ++t) {
    const int kv0 = t * 32;
    const bh_t* kp = qkv + (size_t)(b * TSEQ + kv0 + r16) * (3 * CDIM) + CDIM + h * HDIM + 8 * g;
    const bfx8 ka0 = *(const bfx8*)kp;
    const bfx8 ka1 = *(const bfx8*)(kp + 32);
    const bfx8 kb0 = *(const bfx8*)(kp + 16 * (3 * CDIM));
    const bfx8 kb1 = *(const bfx8*)(kp + 16 * (3 * CDIM) + 32);
    fx4 s0 = {}, s1 = {};
    s0 = mfma16(ka0, qf0, s0); s0 = mfma16(ka1, qf1, s0);   // S^T: [kv][q]
    s1 = mfma16(kb0, qf0, s1); s1 = mfma16(kb1, qf1, s1);

    float mx = -INFINITY;
    float sv0[4], sv1[4];
    #pragma unroll
    for (int rr = 0; rr < 4; ++rr) {
      const int kva = kv0 + 4 * g + rr;
      const int kvb = kva + 16;
      sv0[rr] = (kva <= qidx) ? s0[rr] * 0.125f : -INFINITY;
      sv1[rr] = (kvb <= qidx) ? s1[rr] * 0.125f : -INFINITY;
      mx = fmaxf(mx, fmaxf(sv0[rr], sv1[rr]));
    }
    mx = fmaxf(mx, __shfl_xor(mx, 16));
    mx = fmaxf(mx, __shfl_xor(mx, 32));
    const float mnew = fmaxf(m, mx);
    const float corr = __expf(m - mnew);

    float ps = 0.0f;
    float pv0[4], pv1[4];
    #pragma unroll
    for (int rr = 0; rr < 4; ++rr) {
      pv0[rr] = __expf(sv0[rr] - mnew);
      pv1[rr] = __expf(sv1[rr] - mnew);
      ps += pv0[rr] + pv1[rr];
    }
    ps += __shfl_xor(ps, 16);
    ps += __shfl_xor(ps, 32);
    l = l * corr + ps;
    m = mnew;

    #pragma unroll
    for (int rr = 0; rr < 4; ++rr) {
      const float cr = __shfl(corr, 4 * g + rr);
      o[0][rr] *= cr; o[1][rr] *= cr; o[2][rr] *= cr; o[3][rr] *= cr;
    }

    bfx4 w0, w1;
    #pragma unroll
    for (int rr = 0; rr < 4; ++rr) { w0[rr] = (bh_t)pv0[rr]; w1[rr] = (bh_t)pv1[rr]; }
    *(bfx4*)&P[wave][r16][4 * g]      = w0;
    *(bfx4*)&P[wave][r16][16 + 4 * g] = w1;
    __builtin_amdgcn_wave_barrier();
    const bfx8 pf = *(const bfx8*)&P[wave][r16][8 * g];

    #pragma unroll
    for (int fi = 0; fi < 4; ++fi) {
      const bh_t* vp = vT + (size_t)(bh * HDIM + fi * 16 + r16) * TSEQ + kv0 + 8 * g;
      const bfx8 vf = *(const bfx8*)vp;
      o[fi] = mfma16(pf, vf, o[fi]);
    }
  }

  #pragma unroll
  for (int rr = 0; rr < 4; ++rr) {
    const float lr = __shfl(l, 4 * g + rr);
    const float inv = 1.0f / lr;
    const int trow = b * TSEQ + qbase + 4 * g + rr;
    #pragma unroll
    for (int fi = 0; fi < 4; ++fi)
      outb[(size_t)trow * CDIM + h * HDIM + fi * 16 + r16] = (bh_t)(o[fi][rr] * inv);
  }
}

// ---------------------------------------------------------------------------
// LayerNorm: f32 in -> bf16 out. One wave per row.
// ---------------------------------------------------------------------------
__global__ __launch_bounds__(256) void ln_fwd(
    const float* __restrict__ x, const float* __restrict__ w,
    const float* __restrict__ bb, bh_t* __restrict__ out)
{
  const int wave = threadIdx.x >> 6, lane = threadIdx.x & 63;
  const int row = blockIdx.x * 4 + wave;
  const float* xr = x + (size_t)row * CDIM;
  const int off = lane * 4;
  const float4 v0 = *(const float4*)(xr + off);
  const float4 v1 = *(const float4*)(xr + 256 + off);
  const float4 v2 = *(const float4*)(xr + 512 + off);
  float s  = v0.x + v0.y + v0.z + v0.w + v1.x + v1.y + v1.z + v1.w
           + v2.x + v2.y + v2.z + v2.w;
  float ss = v0.x*v0.x + v0.y*v0.y + v0.z*v0.z + v0.w*v0.w
           + v1.x*v1.x + v1.y*v1.y + v1.z*v1.z + v1.w*v1.w
           + v2.x*v2.x + v2.y*v2.y + v2.z*v2.z + v2.w*v2.w;
  #pragma unroll
  for (int d = 1; d < 64; d <<= 1) { s += __shfl_xor(s, d); ss += __shfl_xor(ss, d); }
  const float mean = s * (1.0f / 768.0f);
  const float inv = rsqrtf(ss * (1.0f / 768.0f) - mean * mean + 1e-5f);
  bh_t* orow = out + (size_t)row * CDIM;

  const float4 w0 = *(const float4*)(w + off),  b0 = *(const float4*)(bb + off);
  const float4 w1 = *(const float4*)(w + 256 + off), b1 = *(const float4*)(bb + 256 + off);
  const float4 w2 = *(const float4*)(w + 512 + off), b2 = *(const float4*)(bb + 512 + off);
  bfx4 o;
  o[0] = (bh_t)((v0.x - mean) * inv * w0.x + b0.x);
  o[1] = (bh_t)((v0.y - mean) * inv * w0.y + b0.y);
  o[2] = (bh_t)((v0.z - mean) * inv * w0.z + b0.z);
  o[3] = (bh_t)((v0.w - mean) * inv * w0.w + b0.w);
  *(bfx4*)(orow + off) = o;
  o[0] = (bh_t)((v1.x - mean) * inv * w1.x + b1.x);
  o[1] = (bh_t)((v1.y - mean) * inv * w1.y + b1.y);
  o[2] = (bh_t)((v1.z - mean) * inv * w1.z + b1.z);
  o[3] = (bh_t)((v1.w - mean) * inv * w1.w + b1.w);
  *(bfx4*)(orow + 256 + off) = o;
  o[0] = (bh_t)((v2.x - mean) * inv * w2.x + b2.x);
  o[1] = (bh_t)((v2.y - mean) * inv * w2.y + b2.y);
  o[2] = (bh_t)((v2.z - mean) * inv * w2.z + b2.z);
  o[3] = (bh_t)((v2.w - mean) * inv * w2.w + b2.w);
  *(bfx4*)(orow + 512 + off) = o;
}

// ---------------------------------------------------------------------------
__global__ void embed_k(const int* __restrict__ ids, const float* __restrict__ tok,
                        const float* __restrict__ pos, float* __restrict__ x)
{
  const int bt = blockIdx.x;
  const int t = bt & (TSEQ - 1);
  const int id = ids[bt];
  const float* tr = tok + (size_t)id * CDIM;
  const float* pr = pos + (size_t)t * CDIM;
  float* xr = x + (size_t)bt * CDIM;
  for (int j = threadIdx.x; j < CDIM; j += 256) xr[j] = tr[j] + pr[j];
}

// transpose + f32->bf16: in [L][R][Cn] -> out [L][Cn][R]
__global__ void tconv(const float* __restrict__ in, bh_t* __restrict__ out, int R, int Cn)
{
  __shared__ float tile[32][33];
  const size_t msz = (size_t)R * Cn;
  in  += msz * blockIdx.z;
  out += msz * blockIdx.z;
  const int tx = threadIdx.x & 31, ty = threadIdx.x >> 5;
  const int c0 = blockIdx.x * 32, r0 = blockIdx.y * 32;
  #pragma unroll
  for (int i = 0; i < 32; i += 8)
    tile[ty + i][tx] = in[(size_t)(r0 + ty + i) * Cn + c0 + tx];
  __syncthreads();
  #pragma unroll
  for (int i = 0; i < 32; i += 8)
    out[(size_t)(c0 + ty + i) * R + r0 + tx] = (bh_t)tile[tx][ty + i];
}

// tok_emb f32 [V][C] -> bf16 [VPAD][C], zero-padded rows
__global__ void embconv(const float* __restrict__ in, bh_t* __restrict__ out)
{
  const size_t i4 = ((size_t)blockIdx.x * 256 + threadIdx.x) * 4;
  const size_t vlim = (size_t)VOCAB * CDIM;
  float4 f = make_float4(0.f, 0.f, 0.f, 0.f);
  if (i4 < vlim) f = *(const float4*)(in + i4);
  bfx4 o;
  o[0] = (bh_t)f.x; o[1] = (bh_t)f.y; o[2] = (bh_t)f.z; o[3] = (bh_t)f.w;
  *(bfx4*)(out + i4) = o;
}

// V slice of qkv -> vT[bh*64 + d][t]
__global__ void vtrans(const bh_t* __restrict__ qkv, bh_t* __restrict__ vT)
{
  __shared__ bh_t tile[32][34];
  const int bh = blockIdx.z;
  const int b = bh / NHEAD, h = bh % NHEAD;
  const int d0 = blockIdx.x * 32, t0 = blockIdx.y * 32;
  const int tx = threadIdx.x & 31, ty = threadIdx.x >> 5;
  #pragma unroll
  for (int i = 0; i < 32; i += 8)
    tile[ty + i][tx] = qkv[(size_t)(b * TSEQ + t0 + ty + i) * (3 * CDIM) + 2 * CDIM + h * HDIM + d0 + tx];
  __syncthreads();
  #pragma unroll
  for (int i = 0; i < 32; i += 8)
    vT[(size_t)(bh * HDIM + d0 + ty + i) * TSEQ + t0 + tx] = tile[tx][ty + i];
}

// ---------------------------------------------------------------------------
extern "C" void kernel_launch(void* const* d_in, const int* in_sizes, int n_in,
                              void* d_out, int out_size, void* d_ws, size_t ws_size,
                              hipStream_t stream)
{
  (void)in_sizes; (void)n_in; (void)out_size; (void)ws_size;
  const int*   ids    = (const int*)d_in[0];
  const float* tok    = (const float*)d_in[1];
  const float* pos    = (const float*)d_in[2];
  const float* qkv_w  = (const float*)d_in[3];
  const float* qkv_b  = (const float*)d_in[4];
  const float* proj_w = (const float*)d_in[5];
  const float* proj_b = (const float*)d_in[6];
  const float* ln1_w  = (const float*)d_in[7];
  const float* ln1_b  = (const float*)d_in[8];
  const float* ln2_w  = (const float*)d_in[9];
  const float* ln2_b  = (const float*)d_in[10];
  const float* fc1_w  = (const float*)d_in[11];
  const float* fc1_b  = (const float*)d_in[12];
  const float* fc2_w  = (const float*)d_in[13];
  const float* fc2_b  = (const float*)d_in[14];
  const float* lnf_w  = (const float*)d_in[15];
  const float* lnf_b  = (const float*)d_in[16];

  // ---- scratch in ws (activations + embT), ~153 MB
  char* wp = (char*)d_ws;
  auto carve = [&](size_t bytes) { char* p = wp; wp += (bytes + 255) & ~(size_t)255; return p; };
  float* x     = (float*)carve((size_t)MROWS * CDIM * 4);
  bh_t*  hbuf  = (bh_t*)carve((size_t)MROWS * CDIM * 2);
  bh_t*  qkvb  = (bh_t*)carve((size_t)MROWS * 3 * CDIM * 2);
  bh_t*  vT    = (bh_t*)carve((size_t)48 * HDIM * TSEQ * 2);
  bh_t*  attno = (bh_t*)carve((size_t)MROWS * CDIM * 2);
  bh_t*  mlp1  = (bh_t*)carve((size_t)MROWS * 3072 * 2);
  bh_t*  embT  = (bh_t*)carve((size_t)VPAD * CDIM * 2);

  // ---- staged in d_out (dead before lm_head overwrites it), ~220 MB of 823
  char* op = (char*)d_out;
  auto carveO = [&](size_t bytes) { char* p = op; op += (bytes + 255) & ~(size_t)255; return p; };
  bh_t* qkvwT  = (bh_t*)carveO((size_t)NLAYER * 3 * CDIM * CDIM * 2);
  bh_t* projwT = (bh_t*)carveO((size_t)NLAYER * CDIM * CDIM * 2);
  bh_t* fc1wT  = (bh_t*)carveO((size_t)NLAYER * 3072 * CDIM * 2);
  bh_t* fc2wT  = (bh_t*)carveO((size_t)NLAYER * CDIM * 3072 * 2);
  float* skpart = (float*)carveO((size_t)4 * MROWS * CDIM * 4);   // split-K partials

  tconv<<<dim3(2304 / 32, 768 / 32, NLAYER), 256, 0, stream>>>(qkv_w, qkvwT, 768, 2304);
  tconv<<<dim3(768 / 32, 768 / 32, NLAYER), 256, 0, stream>>>(proj_w, projwT, 768, 768);
  tconv<<<dim3(3072 / 32, 768 / 32, NLAYER), 256, 0, stream>>>(fc1_w, fc1wT, 768, 3072);
  tconv<<<dim3(768 / 32, 3072 / 32, NLAYER), 256, 0, stream>>>(fc2_w, fc2wT, 3072, 768);
  embconv<<<(VPAD * CDIM / 4) / 256, 256, 0, stream>>>(tok, embT);
  embed_k<<<MROWS, 256, 0, stream>>>(ids, tok, pos, x);

  const size_t pstride = (size_t)MROWS * CDIM;

  for (int l = 0; l < NLAYER; ++l) {
    ln_fwd<<<MROWS / 4, 256, 0, stream>>>(x, ln1_w + l * CDIM, ln1_b + l * CDIM, hbuf);
    gemm_bt<<<dim3(32, 18), 256, 0, stream>>>(hbuf, qkvwT + (size_t)l * 3 * CDIM * CDIM,
        qkv_b + l * 3 * CDIM, nullptr, qkvb, MROWS, 3 * CDIM, CDIM, CDIM, 1 | 8);
    vtrans<<<dim3(2, 32, 48), 256, 0, stream>>>(qkvb, vT);
    attn_fwd<<<768, 256, 0, stream>>>(qkvb, vT, attno);
    // proj: split-K x2 (K=768 -> 2x384), partials then fused reduce(+bias+res)
    for (int s = 0; s < 2; ++s)
      gemm_bt<<<dim3(32, 6), 256, 0, stream>>>(attno + s * 384,
          projwT + (size_t)l * CDIM * CDIM + s * 384, nullptr, nullptr,
          skpart + s * pstride, MROWS, CDIM, 384, CDIM, 0);
    sk_reduce<<<(MROWS * CDIM / 4) / 256, 256, 0, stream>>>(skpart, proj_b + l * CDIM, x, CDIM, 2);
    ln_fwd<<<MROWS / 4, 256, 0, stream>>>(x, ln2_w + l * CDIM, ln2_b + l * CDIM, hbuf);
    gemm_bt<<<dim3(32, 24), 256, 0, stream>>>(hbuf, fc1wT + (size_t)l * 3072 * CDIM,
        fc1_b + l * 3072, nullptr, mlp1, MROWS, 3072, CDIM, CDIM, 1 | 4 | 8);
    // fc2: split-K x4 (K=3072 -> 4x768)
    for (int s = 0; s < 4; ++s)
      gemm_bt<<<dim3(32, 6), 256, 0, stream>>>(mlp1 + s * 768,
          fc2wT + (size_t)l * CDIM * 3072 + s * 768, nullptr, nullptr,
          skpart + s * pstride, MROWS, CDIM, 768, 3072, 0);
    sk_reduce<<<(MROWS * CDIM / 4) / 256, 256, 0, stream>>>(skpart, fc2_b + l * CDIM, x, CDIM, 4);
  }
  ln_fwd<<<MROWS / 4, 256, 0, stream>>>(x, lnf_w, lnf_b, hbuf);
  gemm_lm<<<dim3(MROWS / 256, VPAD / 128), 512, 0, stream>>>(hbuf, embT,
      (float*)d_out, MROWS, VOCAB, CDIM);
}

// Round 3
// 5129.175 us; speedup vs baseline: 1.1686x; 1.1686x over previous
//
#include <hip/hip_runtime.h>
#include <hip/hip_bf16.h>

// GPT-2 small forward on gfx950. bf16 MFMA GEMMs (f32 accum), flash attention.
// R3: revert nontemporal stores (R2: 2x write amplification, +350us);
//     BK=64 (half the barrier drains); XCD-chunked swizzle for lm_head;
//     split-K via blockIdx.z (single dispatch, 768 blocks) for proj/fc2.

typedef __bf16 bh_t;
typedef __bf16 bfx4 __attribute__((ext_vector_type(4)));
typedef __bf16 bfx8 __attribute__((ext_vector_type(8)));
typedef float  fx4  __attribute__((ext_vector_type(4)));

#define CDIM 768
#define TSEQ 1024
#define NHEAD 12
#define HDIM 64
#define NLAYER 12
#define MROWS 4096          // B*T
#define VOCAB 50257
#define VPAD  50304         // 393 * 128

__device__ __forceinline__ void gload_lds16(const void* g, void* l) {
  __builtin_amdgcn_global_load_lds(
      (const __attribute__((address_space(1))) void*)g,
      (__attribute__((address_space(3))) void*)l, 16, 0, 0);
}

__device__ __forceinline__ fx4 mfma16(bfx8 a, bfx8 b, fx4 c) {
  return __builtin_amdgcn_mfma_f32_16x16x32_bf16(a, b, c, 0, 0, 0);
}

// ---------------------------------------------------------------------------
// GEMM: C[M,N] = A[M,K'] @ B^T[N,K']  (+bias, +gelu, +residual)
// 128x128 tile, BK=64, 4 waves (2x2). lda = row stride of A and B (>= K).
// blockIdx.z = split-K slice: A,B advance z*K along k; out -> f32 partial z.
// flags: 1=bias, 2=residual(f32 ld=N), 4=gelu, 8=out bf16, 16=XCD swizzle.
// K must be a multiple of 64; M,N tiles of 128 (N may be ragged: col guard).
// ---------------------------------------------------------------------------
__global__ __launch_bounds__(256, 3) void gemm_bt(
    const bh_t* __restrict__ A, const bh_t* __restrict__ B,
    const float* __restrict__ bias, const float* __restrict__ resid,
    void* __restrict__ outp, int M, int N, int K, int lda, int flags)
{
  __shared__ bh_t As[8][128][8];   // [k-block][row][8 contiguous k]
  __shared__ bh_t Bs[8][128][8];
  const int tid  = threadIdx.x;
  const int wave = tid >> 6, lane = tid & 63;
  const int g = lane >> 4, r16 = lane & 15;

  int bx = blockIdx.x, by = blockIdx.y;
  if (flags & 16) {   // XCD-chunked bijective swizzle (nwg % 8 == 0)
    const int nwg = gridDim.x * gridDim.y;
    int id = by * gridDim.x + bx;
    id = (id & 7) * (nwg >> 3) + (id >> 3);
    bx = id % gridDim.x; by = id / gridDim.x;
  }
  const int m0 = bx * 128, n0 = by * 128;
  const int wm = (wave >> 1) * 64, wn = (wave & 1) * 64;

  if (gridDim.z > 1) {   // split-K: advance along k
    A += (size_t)blockIdx.z * K;
    B += (size_t)blockIdx.z * K;
  }

  fx4 acc[4][4] = {};
  bh_t* AsF = &As[0][0][0];
  bh_t* BsF = &Bs[0][0][0];

  for (int k0 = 0; k0 < K; k0 += 64) {
    #pragma unroll
    for (int j = 0; j < 4; ++j) {
      const int c = tid + j * 256;
      const int row = c & 127, kb = c >> 7;
      gload_lds16(A + (size_t)(m0 + row) * lda + k0 + kb * 8,
                  AsF + (size_t)(j * 256 + wave * 64) * 8);
      gload_lds16(B + (size_t)(n0 + row) * lda + k0 + kb * 8,
                  BsF + (size_t)(j * 256 + wave * 64) * 8);
    }
    __syncthreads();   // drains vmcnt -> LDS tiles ready
    #pragma unroll
    for (int half = 0; half < 2; ++half) {
      bfx8 af[4], bfr[4];
      #pragma unroll
      for (int mi = 0; mi < 4; ++mi) af[mi]  = *(const bfx8*)&As[half * 4 + g][wm + mi * 16 + r16][0];
      #pragma unroll
      for (int ni = 0; ni < 4; ++ni) bfr[ni] = *(const bfx8*)&Bs[half * 4 + g][wn + ni * 16 + r16][0];
      #pragma unroll
      for (int mi = 0; mi < 4; ++mi)
        #pragma unroll
        for (int ni = 0; ni < 4; ++ni)
          acc[mi][ni] = mfma16(af[mi], bfr[ni], acc[mi][ni]);
    }
    __syncthreads();   // all reads done before next stage overwrites
  }

  const bool hasBias = flags & 1, hasRes = flags & 2;
  const bool doGelu  = flags & 4, outBf  = flags & 8;
  float* outF = (float*)outp + (size_t)blockIdx.z * ((size_t)M * N);
  bh_t*  outB = (bh_t*)outp;
  #pragma unroll
  for (int mi = 0; mi < 4; ++mi) {
    #pragma unroll
    for (int ni = 0; ni < 4; ++ni) {
      const int col = n0 + wn + ni * 16 + r16;
      if (col >= N) continue;
      const int rowb = m0 + wm + mi * 16 + 4 * g;
      const float bv = hasBias ? bias[col] : 0.0f;
      #pragma unroll
      for (int rr = 0; rr < 4; ++rr) {
        const size_t idx = (size_t)(rowb + rr) * N + col;
        float v = acc[mi][ni][rr] + bv;
        if (doGelu) v = 0.5f * v * (1.0f + erff(v * 0.70710678118654752f));
        if (hasRes) v += resid[idx];
        if (outBf) outB[idx] = (bh_t)v; else outF[idx] = v;
      }
    }
  }
}

// ---------------------------------------------------------------------------
// split-K reduce: x[idx] = resid(x)[idx] + bias[col] + sum_s part[s][idx]
// ---------------------------------------------------------------------------
__global__ __launch_bounds__(256) void sk_reduce(
    const float* __restrict__ part, const float* __restrict__ bias,
    float* __restrict__ x, int N, int S)
{
  const size_t i4 = ((size_t)blockIdx.x * 256 + threadIdx.x) * 4;
  const size_t stride = (size_t)MROWS * N;
  float4 a = *(const float4*)(part + i4);
  for (int s = 1; s < S; ++s) {
    const float4 p = *(const float4*)(part + s * stride + i4);
    a.x += p.x; a.y += p.y; a.z += p.z; a.w += p.w;
  }
  const int col = (int)(i4 % N);
  const float4 bv = *(const float4*)(bias + col);
  const float4 rv = *(const float4*)(x + i4);
  a.x += bv.x + rv.x; a.y += bv.y + rv.y; a.z += bv.z + rv.z; a.w += bv.w + rv.w;
  *(float4*)(x + i4) = a;
}

// ---------------------------------------------------------------------------
// Flash attention, causal. One wave per (b, h, 16 q-rows).
// ---------------------------------------------------------------------------
__global__ __launch_bounds__(256) void attn_fwd(
    const bh_t* __restrict__ qkv, const bh_t* __restrict__ vT,
    bh_t* __restrict__ outb)
{
  __shared__ bh_t P[4][16][56];
  const int wave = threadIdx.x >> 6, lane = threadIdx.x & 63;
  const int g = lane >> 4, r16 = lane & 15;
  const int gw = blockIdx.x * 4 + wave;
  const int qblk = gw & 63;
  const int bh = gw >> 6;
  const int h = bh % NHEAD, b = bh / NHEAD;
  const int qbase = qblk * 16;
  const int qidx = qbase + r16;

  const bh_t* qp = qkv + (size_t)(b * TSEQ + qbase + r16) * (3 * CDIM) + h * HDIM + 8 * g;
  const bfx8 qf0 = *(const bfx8*)qp;
  const bfx8 qf1 = *(const bfx8*)(qp + 32);

  fx4 o[4] = {};
  float m = -INFINITY, l = 0.0f;
  const int ntiles = qblk / 2 + 1;

  for (int t = 0; t < ntiles; ++t) {
    const int kv0 = t * 32;
    const bh_t* kp = qkv + (size_t)(b * TSEQ + kv0 + r16) * (3 * CDIM) + CDIM + h * HDIM + 8 * g;
    const bfx8 ka0 = *(const bfx8*)kp;
    const bfx8 ka1 = *(const bfx8*)(kp + 32);
    const bfx8 kb0 = *(const bfx8*)(kp + 16 * (3 * CDIM));
    const bfx8 kb1 = *(const bfx8*)(kp + 16 * (3 * CDIM) + 32);
    fx4 s0 = {}, s1 = {};
    s0 = mfma16(ka0, qf0, s0); s0 = mfma16(ka1, qf1, s0);   // S^T: [kv][q]
    s1 = mfma16(kb0, qf0, s1); s1 = mfma16(kb1, qf1, s1);

    float mx = -INFINITY;
    float sv0[4], sv1[4];
    #pragma unroll
    for (int rr = 0; rr < 4; ++rr) {
      const int kva = kv0 + 4 * g + rr;
      const int kvb = kva + 16;
      sv0[rr] = (kva <= qidx) ? s0[rr] * 0.125f : -INFINITY;
      sv1[rr] = (kvb <= qidx) ? s1[rr] * 0.125f : -INFINITY;
      mx = fmaxf(mx, fmaxf(sv0[rr], sv1[rr]));
    }
    mx = fmaxf(mx, __shfl_xor(mx, 16));
    mx = fmaxf(mx, __shfl_xor(mx, 32));
    const float mnew = fmaxf(m, mx);
    const float corr = __expf(m - mnew);

    float ps = 0.0f;
    float pv0[4], pv1[4];
    #pragma unroll
    for (int rr = 0; rr < 4; ++rr) {
      pv0[rr] = __expf(sv0[rr] - mnew);
      pv1[rr] = __expf(sv1[rr] - mnew);
      ps += pv0[rr] + pv1[rr];
    }
    ps += __shfl_xor(ps, 16);
    ps += __shfl_xor(ps, 32);
    l = l * corr + ps;
    m = mnew;

    #pragma unroll
    for (int rr = 0; rr < 4; ++rr) {
      const float cr = __shfl(corr, 4 * g + rr);
      o[0][rr] *= cr; o[1][rr] *= cr; o[2][rr] *= cr; o[3][rr] *= cr;
    }

    bfx4 w0, w1;
    #pragma unroll
    for (int rr = 0; rr < 4; ++rr) { w0[rr] = (bh_t)pv0[rr]; w1[rr] = (bh_t)pv1[rr]; }
    *(bfx4*)&P[wave][r16][4 * g]      = w0;
    *(bfx4*)&P[wave][r16][16 + 4 * g] = w1;
    __builtin_amdgcn_wave_barrier();
    const bfx8 pf = *(const bfx8*)&P[wave][r16][8 * g];

    #pragma unroll
    for (int fi = 0; fi < 4; ++fi) {
      const bh_t* vp = vT + (size_t)(bh * HDIM + fi * 16 + r16) * TSEQ + kv0 + 8 * g;
      const bfx8 vf = *(const bfx8*)vp;
      o[fi] = mfma16(pf, vf, o[fi]);
    }
  }

  #pragma unroll
  for (int rr = 0; rr < 4; ++rr) {
    const float lr = __shfl(l, 4 * g + rr);
    const float inv = 1.0f / lr;
    const int trow = b * TSEQ + qbase + 4 * g + rr;
    #pragma unroll
    for (int fi = 0; fi < 4; ++fi)
      outb[(size_t)trow * CDIM + h * HDIM + fi * 16 + r16] = (bh_t)(o[fi][rr] * inv);
  }
}

// ---------------------------------------------------------------------------
// LayerNorm: f32 in -> bf16 out. One wave per row.
// ---------------------------------------------------------------------------
__global__ __launch_bounds__(256) void ln_fwd(
    const float* __restrict__ x, const float* __restrict__ w,
    const float* __restrict__ bb, bh_t* __restrict__ out)
{
  const int wave = threadIdx.x >> 6, lane = threadIdx.x & 63;
  const int row = blockIdx.x * 4 + wave;
  const float* xr = x + (size_t)row * CDIM;
  const int off = lane * 4;
  const float4 v0 = *(const float4*)(xr + off);
  const float4 v1 = *(const float4*)(xr + 256 + off);
  const float4 v2 = *(const float4*)(xr + 512 + off);
  float s  = v0.x + v0.y + v0.z + v0.w + v1.x + v1.y + v1.z + v1.w
           + v2.x + v2.y + v2.z + v2.w;
  float ss = v0.x*v0.x + v0.y*v0.y + v0.z*v0.z + v0.w*v0.w
           + v1.x*v1.x + v1.y*v1.y + v1.z*v1.z + v1.w*v1.w
           + v2.x*v2.x + v2.y*v2.y + v2.z*v2.z + v2.w*v2.w;
  #pragma unroll
  for (int d = 1; d < 64; d <<= 1) { s += __shfl_xor(s, d); ss += __shfl_xor(ss, d); }
  const float mean = s * (1.0f / 768.0f);
  const float inv = rsqrtf(ss * (1.0f / 768.0f) - mean * mean + 1e-5f);
  bh_t* orow = out + (size_t)row * CDIM;

  const float4 w0 = *(const float4*)(w + off),  b0 = *(const float4*)(bb + off);
  const float4 w1 = *(const float4*)(w + 256 + off), b1 = *(const float4*)(bb + 256 + off);
  const float4 w2 = *(const float4*)(w + 512 + off), b2 = *(const float4*)(bb + 512 + off);
  bfx4 o;
  o[0] = (bh_t)((v0.x - mean) * inv * w0.x + b0.x);
  o[1] = (bh_t)((v0.y - mean) * inv * w0.y + b0.y);
  o[2] = (bh_t)((v0.z - mean) * inv * w0.z + b0.z);
  o[3] = (bh_t)((v0.w - mean) * inv * w0.w + b0.w);
  *(bfx4*)(orow + off) = o;
  o[0] = (bh_t)((v1.x - mean) * inv * w1.x + b1.x);
  o[1] = (bh_t)((v1.y - mean) * inv * w1.y + b1.y);
  o[2] = (bh_t)((v1.z - mean) * inv * w1.z + b1.z);
  o[3] = (bh_t)((v1.w - mean) * inv * w1.w + b1.w);
  *(bfx4*)(orow + 256 + off) = o;
  o[0] = (bh_t)((v2.x - mean) * inv * w2.x + b2.x);
  o[1] = (bh_t)((v2.y - mean) * inv * w2.y + b2.y);
  o[2] = (bh_t)((v2.z - mean) * inv * w2.z + b2.z);
  o[3] = (bh_t)((v2.w - mean) * inv * w2.w + b2.w);
  *(bfx4*)(orow + 512 + off) = o;
}

// ---------------------------------------------------------------------------
__global__ void embed_k(const int* __restrict__ ids, const float* __restrict__ tok,
                        const float* __restrict__ pos, float* __restrict__ x)
{
  const int bt = blockIdx.x;
  const int t = bt & (TSEQ - 1);
  const int id = ids[bt];
  const float* tr = tok + (size_t)id * CDIM;
  const float* pr = pos + (size_t)t * CDIM;
  float* xr = x + (size_t)bt * CDIM;
  for (int j = threadIdx.x; j < CDIM; j += 256) xr[j] = tr[j] + pr[j];
}

// transpose + f32->bf16: in [L][R][Cn] -> out [L][Cn][R]
__global__ void tconv(const float* __restrict__ in, bh_t* __restrict__ out, int R, int Cn)
{
  __shared__ float tile[32][33];
  const size_t msz = (size_t)R * Cn;
  in  += msz * blockIdx.z;
  out += msz * blockIdx.z;
  const int tx = threadIdx.x & 31, ty = threadIdx.x >> 5;
  const int c0 = blockIdx.x * 32, r0 = blockIdx.y * 32;
  #pragma unroll
  for (int i = 0; i < 32; i += 8)
    tile[ty + i][tx] = in[(size_t)(r0 + ty + i) * Cn + c0 + tx];
  __syncthreads();
  #pragma unroll
  for (int i = 0; i < 32; i += 8)
    out[(size_t)(c0 + ty + i) * R + r0 + tx] = (bh_t)tile[tx][ty + i];
}

// tok_emb f32 [V][C] -> bf16 [VPAD][C], zero-padded rows
__global__ void embconv(const float* __restrict__ in, bh_t* __restrict__ out)
{
  const size_t i4 = ((size_t)blockIdx.x * 256 + threadIdx.x) * 4;
  const size_t vlim = (size_t)VOCAB * CDIM;
  float4 f = make_float4(0.f, 0.f, 0.f, 0.f);
  if (i4 < vlim) f = *(const float4*)(in + i4);
  bfx4 o;
  o[0] = (bh_t)f.x; o[1] = (bh_t)f.y; o[2] = (bh_t)f.z; o[3] = (bh_t)f.w;
  *(bfx4*)(out + i4) = o;
}

// V slice of qkv -> vT[bh*64 + d][t]
__global__ void vtrans(const bh_t* __restrict__ qkv, bh_t* __restrict__ vT)
{
  __shared__ bh_t tile[32][34];
  const int bh = blockIdx.z;
  const int b = bh / NHEAD, h = bh % NHEAD;
  const int d0 = blockIdx.x * 32, t0 = blockIdx.y * 32;
  const int tx = threadIdx.x & 31, ty = threadIdx.x >> 5;
  #pragma unroll
  for (int i = 0; i < 32; i += 8)
    tile[ty + i][tx] = qkv[(size_t)(b * TSEQ + t0 + ty + i) * (3 * CDIM) + 2 * CDIM + h * HDIM + d0 + tx];
  __syncthreads();
  #pragma unroll
  for (int i = 0; i < 32; i += 8)
    vT[(size_t)(bh * HDIM + d0 + ty + i) * TSEQ + t0 + tx] = tile[tx][ty + i];
}

// ---------------------------------------------------------------------------
extern "C" void kernel_launch(void* const* d_in, const int* in_sizes, int n_in,
                              void* d_out, int out_size, void* d_ws, size_t ws_size,
                              hipStream_t stream)
{
  (void)in_sizes; (void)n_in; (void)out_size; (void)ws_size;
  const int*   ids    = (const int*)d_in[0];
  const float* tok    = (const float*)d_in[1];
  const float* pos    = (const float*)d_in[2];
  const float* qkv_w  = (const float*)d_in[3];
  const float* qkv_b  = (const float*)d_in[4];
  const float* proj_w = (const float*)d_in[5];
  const float* proj_b = (const float*)d_in[6];
  const float* ln1_w  = (const float*)d_in[7];
  const float* ln1_b  = (const float*)d_in[8];
  const float* ln2_w  = (const float*)d_in[9];
  const float* ln2_b  = (const float*)d_in[10];
  const float* fc1_w  = (const float*)d_in[11];
  const float* fc1_b  = (const float*)d_in[12];
  const float* fc2_w  = (const float*)d_in[13];
  const float* fc2_b  = (const float*)d_in[14];
  const float* lnf_w  = (const float*)d_in[15];
  const float* lnf_b  = (const float*)d_in[16];

  // ---- scratch in ws (activations + embT), ~153 MB
  char* wp = (char*)d_ws;
  auto carve = [&](size_t bytes) { char* p = wp; wp += (bytes + 255) & ~(size_t)255; return p; };
  float* x     = (float*)carve((size_t)MROWS * CDIM * 4);
  bh_t*  hbuf  = (bh_t*)carve((size_t)MROWS * CDIM * 2);
  bh_t*  qkvb  = (bh_t*)carve((size_t)MROWS * 3 * CDIM * 2);
  bh_t*  vT    = (bh_t*)carve((size_t)48 * HDIM * TSEQ * 2);
  bh_t*  attno = (bh_t*)carve((size_t)MROWS * CDIM * 2);
  bh_t*  mlp1  = (bh_t*)carve((size_t)MROWS * 3072 * 2);
  bh_t*  embT  = (bh_t*)carve((size_t)VPAD * CDIM * 2);

  // ---- staged in d_out (dead before lm_head overwrites it), ~270 MB of 823
  char* op = (char*)d_out;
  auto carveO = [&](size_t bytes) { char* p = op; op += (bytes + 255) & ~(size_t)255; return p; };
  bh_t* qkvwT  = (bh_t*)carveO((size_t)NLAYER * 3 * CDIM * CDIM * 2);
  bh_t* projwT = (bh_t*)carveO((size_t)NLAYER * CDIM * CDIM * 2);
  bh_t* fc1wT  = (bh_t*)carveO((size_t)NLAYER * 3072 * CDIM * 2);
  bh_t* fc2wT  = (bh_t*)carveO((size_t)NLAYER * CDIM * 3072 * 2);
  float* skpart = (float*)carveO((size_t)4 * MROWS * CDIM * 4);   // split-K partials

  tconv<<<dim3(2304 / 32, 768 / 32, NLAYER), 256, 0, stream>>>(qkv_w, qkvwT, 768, 2304);
  tconv<<<dim3(768 / 32, 768 / 32, NLAYER), 256, 0, stream>>>(proj_w, projwT, 768, 768);
  tconv<<<dim3(3072 / 32, 768 / 32, NLAYER), 256, 0, stream>>>(fc1_w, fc1wT, 768, 3072);
  tconv<<<dim3(768 / 32, 3072 / 32, NLAYER), 256, 0, stream>>>(fc2_w, fc2wT, 3072, 768);
  embconv<<<(VPAD * CDIM / 4) / 256, 256, 0, stream>>>(tok, embT);
  embed_k<<<MROWS, 256, 0, stream>>>(ids, tok, pos, x);

  for (int l = 0; l < NLAYER; ++l) {
    ln_fwd<<<MROWS / 4, 256, 0, stream>>>(x, ln1_w + l * CDIM, ln1_b + l * CDIM, hbuf);
    gemm_bt<<<dim3(32, 18), 256, 0, stream>>>(hbuf, qkvwT + (size_t)l * 3 * CDIM * CDIM,
        qkv_b + l * 3 * CDIM, nullptr, qkvb, MROWS, 3 * CDIM, CDIM, CDIM, 1 | 8);
    vtrans<<<dim3(2, 32, 48), 256, 0, stream>>>(qkvb, vT);
    attn_fwd<<<768, 256, 0, stream>>>(qkvb, vT, attno);
    // proj: split-K x4 in one dispatch (grid z), K_eff=192, 768 blocks
    gemm_bt<<<dim3(32, 6, 4), 256, 0, stream>>>(attno,
        projwT + (size_t)l * CDIM * CDIM, nullptr, nullptr,
        skpart, MROWS, CDIM, 192, CDIM, 0);
    sk_reduce<<<(MROWS * CDIM / 4) / 256, 256, 0, stream>>>(skpart, proj_b + l * CDIM, x, CDIM, 4);
    ln_fwd<<<MROWS / 4, 256, 0, stream>>>(x, ln2_w + l * CDIM, ln2_b + l * CDIM, hbuf);
    gemm_bt<<<dim3(32, 24), 256, 0, stream>>>(hbuf, fc1wT + (size_t)l * 3072 * CDIM,
        fc1_b + l * 3072, nullptr, mlp1, MROWS, 3072, CDIM, CDIM, 1 | 4 | 8);
    // fc2: split-K x4 in one dispatch, K_eff=768, 768 blocks
    gemm_bt<<<dim3(32, 6, 4), 256, 0, stream>>>(mlp1,
        fc2wT + (size_t)l * CDIM * 3072, nullptr, nullptr,
        skpart, MROWS, CDIM, 768, 3072, 0);
    sk_reduce<<<(MROWS * CDIM / 4) / 256, 256, 0, stream>>>(skpart, fc2_b + l * CDIM, x, CDIM, 4);
  }
  ln_fwd<<<MROWS / 4, 256, 0, stream>>>(x, lnf_w, lnf_b, hbuf);
  gemm_bt<<<dim3(32, VPAD / 128), 256, 0, stream>>>(hbuf, embT, nullptr, nullptr,
      (float*)d_out, MROWS, VOCAB, CDIM, CDIM, 16);
}

// Round 4
// 4726.891 us; speedup vs baseline: 1.2680x; 1.0851x over previous
//
#include <hip/hip_runtime.h>
#include <hip/hip_bf16.h>

// GPT-2 small forward on gfx950. bf16 MFMA GEMMs (f32 accum), flash attention.
// R4: gemm_bt gets T3 2-phase double-buffered prefetch (stage t+1 before
//     computing t; ONE barrier per K-step, vmcnt drain lands after MFMA);
//     lm_head XCD swizzle reverted (R3: FETCH 352MB->1.25GB, A-sweep thrash).

typedef __bf16 bh_t;
typedef __bf16 bfx4 __attribute__((ext_vector_type(4)));
typedef __bf16 bfx8 __attribute__((ext_vector_type(8)));
typedef float  fx4  __attribute__((ext_vector_type(4)));

#define CDIM 768
#define TSEQ 1024
#define NHEAD 12
#define HDIM 64
#define NLAYER 12
#define MROWS 4096          // B*T
#define VOCAB 50257
#define VPAD  50304         // 393 * 128

__device__ __forceinline__ void gload_lds16(const void* g, void* l) {
  __builtin_amdgcn_global_load_lds(
      (const __attribute__((address_space(1))) void*)g,
      (__attribute__((address_space(3))) void*)l, 16, 0, 0);
}

__device__ __forceinline__ fx4 mfma16(bfx8 a, bfx8 b, fx4 c) {
  return __builtin_amdgcn_mfma_f32_16x16x32_bf16(a, b, c, 0, 0, 0);
}

// ---------------------------------------------------------------------------
// GEMM: C[M,N] = A[M,K'] @ B^T[N,K']  (+bias, +gelu, +residual)
// 128x128 tile, BK=32, 4 waves (2x2), double-buffered LDS prefetch (T3 2-phase).
// lda = row stride of A and B (>= K). blockIdx.z = split-K slice (advance z*K).
// flags: 1=bias, 2=residual(f32 ld=N), 4=gelu, 8=out bf16.
// K % 32 == 0; M % 128 == 0; N may be ragged (col guard in epilogue).
// ---------------------------------------------------------------------------
__global__ __launch_bounds__(256, 4) void gemm_bt(
    const bh_t* __restrict__ A, const bh_t* __restrict__ B,
    const float* __restrict__ bias, const float* __restrict__ resid,
    void* __restrict__ outp, int M, int N, int K, int lda, int flags)
{
  __shared__ bh_t As[2][4][128][8];   // [buf][k-block][row][8 contiguous k]
  __shared__ bh_t Bs[2][4][128][8];
  const int tid  = threadIdx.x;
  const int wave = tid >> 6, lane = tid & 63;
  const int g = lane >> 4, r16 = lane & 15;
  const int m0 = blockIdx.x * 128, n0 = blockIdx.y * 128;
  const int wm = (wave >> 1) * 64, wn = (wave & 1) * 64;

  const bh_t* Ab = A;
  const bh_t* Bb = B;
  if (gridDim.z > 1) {   // split-K: advance along k
    Ab += (size_t)blockIdx.z * K;
    Bb += (size_t)blockIdx.z * K;
  }
  Ab += (size_t)m0 * lda;
  Bb += (size_t)n0 * lda;

  const int c0 = tid, c1 = tid + 256;
  const int row0 = c0 & 127, kb0 = c0 >> 7;
  const int row1 = c1 & 127, kb1 = c1 >> 7;

  fx4 acc[4][4] = {};

  // stage K-step k0 into buffer `buf` (dst linear = c*16B, matches [kb][row])
  auto stage = [&](int buf, int k0) {
    bh_t* AsF = &As[buf][0][0][0];
    bh_t* BsF = &Bs[buf][0][0][0];
    gload_lds16(Ab + (size_t)row0 * lda + k0 + kb0 * 8, AsF + (size_t)(wave * 64) * 8);
    gload_lds16(Ab + (size_t)row1 * lda + k0 + kb1 * 8, AsF + (size_t)(256 + wave * 64) * 8);
    gload_lds16(Bb + (size_t)row0 * lda + k0 + kb0 * 8, BsF + (size_t)(wave * 64) * 8);
    gload_lds16(Bb + (size_t)row1 * lda + k0 + kb1 * 8, BsF + (size_t)(256 + wave * 64) * 8);
  };

  stage(0, 0);
  __syncthreads();                    // tile 0 ready
  const int nk = K >> 5;
  int cur = 0;
  for (int t = 0; t < nk; ++t) {
    if (t + 1 < nk) stage(cur ^ 1, (t + 1) << 5);   // prefetch next tile
    bfx8 af[4], bfr[4];
    #pragma unroll
    for (int mi = 0; mi < 4; ++mi) af[mi]  = *(const bfx8*)&As[cur][g][wm + mi * 16 + r16][0];
    #pragma unroll
    for (int ni = 0; ni < 4; ++ni) bfr[ni] = *(const bfx8*)&Bs[cur][g][wn + ni * 16 + r16][0];
    #pragma unroll
    for (int mi = 0; mi < 4; ++mi)
      #pragma unroll
      for (int ni = 0; ni < 4; ++ni)
        acc[mi][ni] = mfma16(af[mi], bfr[ni], acc[mi][ni]);
    __syncthreads();   // drains vmcnt (prefetch landed) + all reads of cur done
    cur ^= 1;
  }

  const bool hasBias = flags & 1, hasRes = flags & 2;
  const bool doGelu  = flags & 4, outBf  = flags & 8;
  float* outF = (float*)outp + (size_t)blockIdx.z * ((size_t)M * N);
  bh_t*  outB = (bh_t*)outp;
  #pragma unroll
  for (int mi = 0; mi < 4; ++mi) {
    #pragma unroll
    for (int ni = 0; ni < 4; ++ni) {
      const int col = n0 + wn + ni * 16 + r16;
      if (col >= N) continue;
      const int rowb = m0 + wm + mi * 16 + 4 * g;
      const float bv = hasBias ? bias[col] : 0.0f;
      #pragma unroll
      for (int rr = 0; rr < 4; ++rr) {
        const size_t idx = (size_t)(rowb + rr) * N + col;
        float v = acc[mi][ni][rr] + bv;
        if (doGelu) v = 0.5f * v * (1.0f + erff(v * 0.70710678118654752f));
        if (hasRes) v += resid[idx];
        if (outBf) outB[idx] = (bh_t)v; else outF[idx] = v;
      }
    }
  }
}

// ---------------------------------------------------------------------------
// split-K reduce: x[idx] = resid(x)[idx] + bias[col] + sum_s part[s][idx]
// ---------------------------------------------------------------------------
__global__ __launch_bounds__(256) void sk_reduce(
    const float* __restrict__ part, const float* __restrict__ bias,
    float* __restrict__ x, int N, int S)
{
  const size_t i4 = ((size_t)blockIdx.x * 256 + threadIdx.x) * 4;
  const size_t stride = (size_t)MROWS * N;
  float4 a = *(const float4*)(part + i4);
  for (int s = 1; s < S; ++s) {
    const float4 p = *(const float4*)(part + s * stride + i4);
    a.x += p.x; a.y += p.y; a.z += p.z; a.w += p.w;
  }
  const int col = (int)(i4 % N);
  const float4 bv = *(const float4*)(bias + col);
  const float4 rv = *(const float4*)(x + i4);
  a.x += bv.x + rv.x; a.y += bv.y + rv.y; a.z += bv.z + rv.z; a.w += bv.w + rv.w;
  *(float4*)(x + i4) = a;
}

// ---------------------------------------------------------------------------
// Flash attention, causal. One wave per (b, h, 16 q-rows).
// ---------------------------------------------------------------------------
__global__ __launch_bounds__(256) void attn_fwd(
    const bh_t* __restrict__ qkv, const bh_t* __restrict__ vT,
    bh_t* __restrict__ outb)
{
  __shared__ bh_t P[4][16][56];
  const int wave = threadIdx.x >> 6, lane = threadIdx.x & 63;
  const int g = lane >> 4, r16 = lane & 15;
  const int gw = blockIdx.x * 4 + wave;
  const int qblk = gw & 63;
  const int bh = gw >> 6;
  const int h = bh % NHEAD, b = bh / NHEAD;
  const int qbase = qblk * 16;
  const int qidx = qbase + r16;

  const bh_t* qp = qkv + (size_t)(b * TSEQ + qbase + r16) * (3 * CDIM) + h * HDIM + 8 * g;
  const bfx8 qf0 = *(const bfx8*)qp;
  const bfx8 qf1 = *(const bfx8*)(qp + 32);

  fx4 o[4] = {};
  float m = -INFINITY, l = 0.0f;
  const int ntiles = qblk / 2 + 1;

  for (int t = 0; t < ntiles; ++t) {
    const int kv0 = t * 32;
    const bh_t* kp = qkv + (size_t)(b * TSEQ + kv0 + r16) * (3 * CDIM) + CDIM + h * HDIM + 8 * g;
    const bfx8 ka0 = *(const bfx8*)kp;
    const bfx8 ka1 = *(const bfx8*)(kp + 32);
    const bfx8 kb0 = *(const bfx8*)(kp + 16 * (3 * CDIM));
    const bfx8 kb1 = *(const bfx8*)(kp + 16 * (3 * CDIM) + 32);
    fx4 s0 = {}, s1 = {};
    s0 = mfma16(ka0, qf0, s0); s0 = mfma16(ka1, qf1, s0);   // S^T: [kv][q]
    s1 = mfma16(kb0, qf0, s1); s1 = mfma16(kb1, qf1, s1);

    float mx = -INFINITY;
    float sv0[4], sv1[4];
    #pragma unroll
    for (int rr = 0; rr < 4; ++rr) {
      const int kva = kv0 + 4 * g + rr;
      const int kvb = kva + 16;
      sv0[rr] = (kva <= qidx) ? s0[rr] * 0.125f : -INFINITY;
      sv1[rr] = (kvb <= qidx) ? s1[rr] * 0.125f : -INFINITY;
      mx = fmaxf(mx, fmaxf(sv0[rr], sv1[rr]));
    }
    mx = fmaxf(mx, __shfl_xor(mx, 16));
    mx = fmaxf(mx, __shfl_xor(mx, 32));
    const float mnew = fmaxf(m, mx);
    const float corr = __expf(m - mnew);

    float ps = 0.0f;
    float pv0[4], pv1[4];
    #pragma unroll
    for (int rr = 0; rr < 4; ++rr) {
      pv0[rr] = __expf(sv0[rr] - mnew);
      pv1[rr] = __expf(sv1[rr] - mnew);
      ps += pv0[rr] + pv1[rr];
    }
    ps += __shfl_xor(ps, 16);
    ps += __shfl_xor(ps, 32);
    l = l * corr + ps;
    m = mnew;

    #pragma unroll
    for (int rr = 0; rr < 4; ++rr) {
      const float cr = __shfl(corr, 4 * g + rr);
      o[0][rr] *= cr; o[1][rr] *= cr; o[2][rr] *= cr; o[3][rr] *= cr;
    }

    bfx4 w0, w1;
    #pragma unroll
    for (int rr = 0; rr < 4; ++rr) { w0[rr] = (bh_t)pv0[rr]; w1[rr] = (bh_t)pv1[rr]; }
    *(bfx4*)&P[wave][r16][4 * g]      = w0;
    *(bfx4*)&P[wave][r16][16 + 4 * g] = w1;
    __builtin_amdgcn_wave_barrier();
    const bfx8 pf = *(const bfx8*)&P[wave][r16][8 * g];

    #pragma unroll
    for (int fi = 0; fi < 4; ++fi) {
      const bh_t* vp = vT + (size_t)(bh * HDIM + fi * 16 + r16) * TSEQ + kv0 + 8 * g;
      const bfx8 vf = *(const bfx8*)vp;
      o[fi] = mfma16(pf, vf, o[fi]);
    }
  }

  #pragma unroll
  for (int rr = 0; rr < 4; ++rr) {
    const float lr = __shfl(l, 4 * g + rr);
    const float inv = 1.0f / lr;
    const int trow = b * TSEQ + qbase + 4 * g + rr;
    #pragma unroll
    for (int fi = 0; fi < 4; ++fi)
      outb[(size_t)trow * CDIM + h * HDIM + fi * 16 + r16] = (bh_t)(o[fi][rr] * inv);
  }
}

// ---------------------------------------------------------------------------
// LayerNorm: f32 in -> bf16 out. One wave per row.
// ---------------------------------------------------------------------------
__global__ __launch_bounds__(256) void ln_fwd(
    const float* __restrict__ x, const float* __restrict__ w,
    const float* __restrict__ bb, bh_t* __restrict__ out)
{
  const int wave = threadIdx.x >> 6, lane = threadIdx.x & 63;
  const int row = blockIdx.x * 4 + wave;
  const float* xr = x + (size_t)row * CDIM;
  const int off = lane * 4;
  const float4 v0 = *(const float4*)(xr + off);
  const float4 v1 = *(const float4*)(xr + 256 + off);
  const float4 v2 = *(const float4*)(xr + 512 + off);
  float s  = v0.x + v0.y + v0.z + v0.w + v1.x + v1.y + v1.z + v1.w
           + v2.x + v2.y + v2.z + v2.w;
  float ss = v0.x*v0.x + v0.y*v0.y + v0.z*v0.z + v0.w*v0.w
           + v1.x*v1.x + v1.y*v1.y + v1.z*v1.z + v1.w*v1.w
           + v2.x*v2.x + v2.y*v2.y + v2.z*v2.z + v2.w*v2.w;
  #pragma unroll
  for (int d = 1; d < 64; d <<= 1) { s += __shfl_xor(s, d); ss += __shfl_xor(ss, d); }
  const float mean = s * (1.0f / 768.0f);
  const float inv = rsqrtf(ss * (1.0f / 768.0f) - mean * mean + 1e-5f);
  bh_t* orow = out + (size_t)row * CDIM;

  const float4 w0 = *(const float4*)(w + off),  b0 = *(const float4*)(bb + off);
  const float4 w1 = *(const float4*)(w + 256 + off), b1 = *(const float4*)(bb + 256 + off);
  const float4 w2 = *(const float4*)(w + 512 + off), b2 = *(const float4*)(bb + 512 + off);
  bfx4 o;
  o[0] = (bh_t)((v0.x - mean) * inv * w0.x + b0.x);
  o[1] = (bh_t)((v0.y - mean) * inv * w0.y + b0.y);
  o[2] = (bh_t)((v0.z - mean) * inv * w0.z + b0.z);
  o[3] = (bh_t)((v0.w - mean) * inv * w0.w + b0.w);
  *(bfx4*)(orow + off) = o;
  o[0] = (bh_t)((v1.x - mean) * inv * w1.x + b1.x);
  o[1] = (bh_t)((v1.y - mean) * inv * w1.y + b1.y);
  o[2] = (bh_t)((v1.z - mean) * inv * w1.z + b1.z);
  o[3] = (bh_t)((v1.w - mean) * inv * w1.w + b1.w);
  *(bfx4*)(orow + 256 + off) = o;
  o[0] = (bh_t)((v2.x - mean) * inv * w2.x + b2.x);
  o[1] = (bh_t)((v2.y - mean) * inv * w2.y + b2.y);
  o[2] = (bh_t)((v2.z - mean) * inv * w2.z + b2.z);
  o[3] = (bh_t)((v2.w - mean) * inv * w2.w + b2.w);
  *(bfx4*)(orow + 512 + off) = o;
}

// ---------------------------------------------------------------------------
__global__ void embed_k(const int* __restrict__ ids, const float* __restrict__ tok,
                        const float* __restrict__ pos, float* __restrict__ x)
{
  const int bt = blockIdx.x;
  const int t = bt & (TSEQ - 1);
  const int id = ids[bt];
  const float* tr = tok + (size_t)id * CDIM;
  const float* pr = pos + (size_t)t * CDIM;
  float* xr = x + (size_t)bt * CDIM;
  for (int j = threadIdx.x; j < CDIM; j += 256) xr[j] = tr[j] + pr[j];
}

// transpose + f32->bf16: in [L][R][Cn] -> out [L][Cn][R]
__global__ void tconv(const float* __restrict__ in, bh_t* __restrict__ out, int R, int Cn)
{
  __shared__ float tile[32][33];
  const size_t msz = (size_t)R * Cn;
  in  += msz * blockIdx.z;
  out += msz * blockIdx.z;
  const int tx = threadIdx.x & 31, ty = threadIdx.x >> 5;
  const int c0 = blockIdx.x * 32, r0 = blockIdx.y * 32;
  #pragma unroll
  for (int i = 0; i < 32; i += 8)
    tile[ty + i][tx] = in[(size_t)(r0 + ty + i) * Cn + c0 + tx];
  __syncthreads();
  #pragma unroll
  for (int i = 0; i < 32; i += 8)
    out[(size_t)(c0 + ty + i) * R + r0 + tx] = (bh_t)tile[tx][ty + i];
}

// tok_emb f32 [V][C] -> bf16 [VPAD][C], zero-padded rows
__global__ void embconv(const float* __restrict__ in, bh_t* __restrict__ out)
{
  const size_t i4 = ((size_t)blockIdx.x * 256 + threadIdx.x) * 4;
  const size_t vlim = (size_t)VOCAB * CDIM;
  float4 f = make_float4(0.f, 0.f, 0.f, 0.f);
  if (i4 < vlim) f = *(const float4*)(in + i4);
  bfx4 o;
  o[0] = (bh_t)f.x; o[1] = (bh_t)f.y; o[2] = (bh_t)f.z; o[3] = (bh_t)f.w;
  *(bfx4*)(out + i4) = o;
}

// V slice of qkv -> vT[bh*64 + d][t]
__global__ void vtrans(const bh_t* __restrict__ qkv, bh_t* __restrict__ vT)
{
  __shared__ bh_t tile[32][34];
  const int bh = blockIdx.z;
  const int b = bh / NHEAD, h = bh % NHEAD;
  const int d0 = blockIdx.x * 32, t0 = blockIdx.y * 32;
  const int tx = threadIdx.x & 31, ty = threadIdx.x >> 5;
  #pragma unroll
  for (int i = 0; i < 32; i += 8)
    tile[ty + i][tx] = qkv[(size_t)(b * TSEQ + t0 + ty + i) * (3 * CDIM) + 2 * CDIM + h * HDIM + d0 + tx];
  __syncthreads();
  #pragma unroll
  for (int i = 0; i < 32; i += 8)
    vT[(size_t)(bh * HDIM + d0 + ty + i) * TSEQ + t0 + tx] = tile[tx][ty + i];
}

// ---------------------------------------------------------------------------
extern "C" void kernel_launch(void* const* d_in, const int* in_sizes, int n_in,
                              void* d_out, int out_size, void* d_ws, size_t ws_size,
                              hipStream_t stream)
{
  (void)in_sizes; (void)n_in; (void)out_size; (void)ws_size;
  const int*   ids    = (const int*)d_in[0];
  const float* tok    = (const float*)d_in[1];
  const float* pos    = (const float*)d_in[2];
  const float* qkv_w  = (const float*)d_in[3];
  const float* qkv_b  = (const float*)d_in[4];
  const float* proj_w = (const float*)d_in[5];
  const float* proj_b = (const float*)d_in[6];
  const float* ln1_w  = (const float*)d_in[7];
  const float* ln1_b  = (const float*)d_in[8];
  const float* ln2_w  = (const float*)d_in[9];
  const float* ln2_b  = (const float*)d_in[10];
  const float* fc1_w  = (const float*)d_in[11];
  const float* fc1_b  = (const float*)d_in[12];
  const float* fc2_w  = (const float*)d_in[13];
  const float* fc2_b  = (const float*)d_in[14];
  const float* lnf_w  = (const float*)d_in[15];
  const float* lnf_b  = (const float*)d_in[16];

  // ---- scratch in ws (activations + embT), ~153 MB
  char* wp = (char*)d_ws;
  auto carve = [&](size_t bytes) { char* p = wp; wp += (bytes + 255) & ~(size_t)255; return p; };
  float* x     = (float*)carve((size_t)MROWS * CDIM * 4);
  bh_t*  hbuf  = (bh_t*)carve((size_t)MROWS * CDIM * 2);
  bh_t*  qkvb  = (bh_t*)carve((size_t)MROWS * 3 * CDIM * 2);
  bh_t*  vT    = (bh_t*)carve((size_t)48 * HDIM * TSEQ * 2);
  bh_t*  attno = (bh_t*)carve((size_t)MROWS * CDIM * 2);
  bh_t*  mlp1  = (bh_t*)carve((size_t)MROWS * 3072 * 2);
  bh_t*  embT  = (bh_t*)carve((size_t)VPAD * CDIM * 2);

  // ---- staged in d_out (dead before lm_head overwrites it), ~270 MB of 823
  char* op = (char*)d_out;
  auto carveO = [&](size_t bytes) { char* p = op; op += (bytes + 255) & ~(size_t)255; return p; };
  bh_t* qkvwT  = (bh_t*)carveO((size_t)NLAYER * 3 * CDIM * CDIM * 2);
  bh_t* projwT = (bh_t*)carveO((size_t)NLAYER * CDIM * CDIM * 2);
  bh_t* fc1wT  = (bh_t*)carveO((size_t)NLAYER * 3072 * CDIM * 2);
  bh_t* fc2wT  = (bh_t*)carveO((size_t)NLAYER * CDIM * 3072 * 2);
  float* skpart = (float*)carveO((size_t)4 * MROWS * CDIM * 4);   // split-K partials

  tconv<<<dim3(2304 / 32, 768 / 32, NLAYER), 256, 0, stream>>>(qkv_w, qkvwT, 768, 2304);
  tconv<<<dim3(768 / 32, 768 / 32, NLAYER), 256, 0, stream>>>(proj_w, projwT, 768, 768);
  tconv<<<dim3(3072 / 32, 768 / 32, NLAYER), 256, 0, stream>>>(fc1_w, fc1wT, 768, 3072);
  tconv<<<dim3(768 / 32, 3072 / 32, NLAYER), 256, 0, stream>>>(fc2_w, fc2wT, 3072, 768);
  embconv<<<(VPAD * CDIM / 4) / 256, 256, 0, stream>>>(tok, embT);
  embed_k<<<MROWS, 256, 0, stream>>>(ids, tok, pos, x);

  for (int l = 0; l < NLAYER; ++l) {
    ln_fwd<<<MROWS / 4, 256, 0, stream>>>(x, ln1_w + l * CDIM, ln1_b + l * CDIM, hbuf);
    gemm_bt<<<dim3(32, 18), 256, 0, stream>>>(hbuf, qkvwT + (size_t)l * 3 * CDIM * CDIM,
        qkv_b + l * 3 * CDIM, nullptr, qkvb, MROWS, 3 * CDIM, CDIM, CDIM, 1 | 8);
    vtrans<<<dim3(2, 32, 48), 256, 0, stream>>>(qkvb, vT);
    attn_fwd<<<768, 256, 0, stream>>>(qkvb, vT, attno);
    // proj: split-K x4 in one dispatch (grid z), K_eff=192, 768 blocks
    gemm_bt<<<dim3(32, 6, 4), 256, 0, stream>>>(attno,
        projwT + (size_t)l * CDIM * CDIM, nullptr, nullptr,
        skpart, MROWS, CDIM, 192, CDIM, 0);
    sk_reduce<<<(MROWS * CDIM / 4) / 256, 256, 0, stream>>>(skpart, proj_b + l * CDIM, x, CDIM, 4);
    ln_fwd<<<MROWS / 4, 256, 0, stream>>>(x, ln2_w + l * CDIM, ln2_b + l * CDIM, hbuf);
    gemm_bt<<<dim3(32, 24), 256, 0, stream>>>(hbuf, fc1wT + (size_t)l * 3072 * CDIM,
        fc1_b + l * 3072, nullptr, mlp1, MROWS, 3072, CDIM, CDIM, 1 | 4 | 8);
    // fc2: split-K x4 in one dispatch, K_eff=768, 768 blocks
    gemm_bt<<<dim3(32, 6, 4), 256, 0, stream>>>(mlp1,
        fc2wT + (size_t)l * CDIM * 3072, nullptr, nullptr,
        skpart, MROWS, CDIM, 768, 3072, 0);
    sk_reduce<<<(MROWS * CDIM / 4) / 256, 256, 0, stream>>>(skpart, fc2_b + l * CDIM, x, CDIM, 4);
  }
  ln_fwd<<<MROWS / 4, 256, 0, stream>>>(x, lnf_w, lnf_b, hbuf);
  gemm_bt<<<dim3(32, VPAD / 128), 256, 0, stream>>>(hbuf, embT, nullptr, nullptr,
      (float*)d_out, MROWS, VOCAB, CDIM, CDIM, 0);
}

// Round 5
// 4665.005 us; speedup vs baseline: 1.2849x; 1.0133x over previous
//
#include <hip/hip_runtime.h>
#include <hip/hip_bf16.h>

// GPT-2 small forward on gfx950. bf16 MFMA GEMMs (f32 accum), flash attention.
// R5: gemm_bt -> 3-buffer software pipeline with counted vmcnt(4) + raw
//     s_barrier (never drain to 0 in-loop). Buffers are DISTINCT __shared__
//     symbols + loop unrolled x3 so buffer indices are static -> alias
//     analysis can prove ds_read(cur) doesn't touch the DMA-target buffer,
//     so no compiler-inserted vmcnt(0) before the fragment reads (the R4
//     failure mode). Requires nk % 3 == 0 (all our K: 768->24, 192->6).

typedef __bf16 bh_t;
typedef __bf16 bfx4 __attribute__((ext_vector_type(4)));
typedef __bf16 bfx8 __attribute__((ext_vector_type(8)));
typedef float  fx4  __attribute__((ext_vector_type(4)));

#define CDIM 768
#define TSEQ 1024
#define NHEAD 12
#define HDIM 64
#define NLAYER 12
#define MROWS 4096          // B*T
#define VOCAB 50257
#define VPAD  50304         // 393 * 128

__device__ __forceinline__ void gload_lds16(const void* g, void* l) {
  __builtin_amdgcn_global_load_lds(
      (const __attribute__((address_space(1))) void*)g,
      (__attribute__((address_space(3))) void*)l, 16, 0, 0);
}

__device__ __forceinline__ fx4 mfma16(bfx8 a, bfx8 b, fx4 c) {
  return __builtin_amdgcn_mfma_f32_16x16x32_bf16(a, b, c, 0, 0, 0);
}

// ---------------------------------------------------------------------------
// GEMM: C[M,N] = A[M,K'] @ B^T[N,K']  (+bias, +gelu, +residual)
// 128x128 tile, BK=32, 4 waves (2x2), 3-deep LDS pipeline, counted vmcnt.
// lda = row stride of A and B (>= K). blockIdx.z = split-K slice (advance z*K).
// flags: 1=bias, 2=residual(f32 ld=N), 4=gelu, 8=out bf16.
// K % 96 == 0 (nk % 3); M % 128 == 0; N may be ragged (col guard in epilogue).
// ---------------------------------------------------------------------------
__global__ __launch_bounds__(256, 3) void gemm_bt(
    const bh_t* __restrict__ A, const bh_t* __restrict__ B,
    const float* __restrict__ bias, const float* __restrict__ resid,
    void* __restrict__ outp, int M, int N, int K, int lda, int flags)
{
  __shared__ bh_t As0[4][128][8], Bs0[4][128][8];   // [k-block][row][8 k]
  __shared__ bh_t As1[4][128][8], Bs1[4][128][8];
  __shared__ bh_t As2[4][128][8], Bs2[4][128][8];
  const int tid  = threadIdx.x;
  const int wave = tid >> 6, lane = tid & 63;
  const int g = lane >> 4, r16 = lane & 15;
  const int m0 = blockIdx.x * 128, n0 = blockIdx.y * 128;
  const int wm = (wave >> 1) * 64, wn = (wave & 1) * 64;

  const bh_t* Ab = A;
  const bh_t* Bb = B;
  if (gridDim.z > 1) {   // split-K: advance along k
    Ab += (size_t)blockIdx.z * K;
    Bb += (size_t)blockIdx.z * K;
  }
  Ab += (size_t)m0 * lda;
  Bb += (size_t)n0 * lda;

  const int row0 = tid & 127, kb0 = tid >> 7;
  const int row1 = row0, kb1 = kb0 + 2;            // tid+256 pattern

  fx4 acc[4][4] = {};
  const int nk = K >> 5;

  // stage K-step t into given buffers (dst linear = wave-uniform + lane*16B)
  auto stageTo = [&](bh_t* AsF, bh_t* BsF, int t) {
    const int k0 = t << 5;
    gload_lds16(Ab + (size_t)row0 * lda + k0 + kb0 * 8, AsF + (size_t)(wave * 64) * 8);
    gload_lds16(Ab + (size_t)row1 * lda + k0 + kb1 * 8, AsF + (size_t)(256 + wave * 64) * 8);
    gload_lds16(Bb + (size_t)row0 * lda + k0 + kb0 * 8, BsF + (size_t)(wave * 64) * 8);
    gload_lds16(Bb + (size_t)row1 * lda + k0 + kb1 * 8, BsF + (size_t)(256 + wave * 64) * 8);
  };

#define GPT_PHASE(CURA, CURB, NXA, NXB, T)                                   \
  {                                                                          \
    if ((T) + 1 < nk) { asm volatile("s_waitcnt vmcnt(4)" ::: "memory"); }   \
    else              { asm volatile("s_waitcnt vmcnt(0)" ::: "memory"); }   \
    __builtin_amdgcn_s_barrier();                                            \
    asm volatile("" ::: "memory");                                           \
    if ((T) + 2 < nk) stageTo(&NXA[0][0][0], &NXB[0][0][0], (T) + 2);        \
    bfx8 af[4], bfr[4];                                                      \
    _Pragma("unroll")                                                        \
    for (int mi = 0; mi < 4; ++mi)                                           \
      af[mi] = *(const bfx8*)&CURA[g][wm + mi * 16 + r16][0];                \
    _Pragma("unroll")                                                        \
    for (int ni = 0; ni < 4; ++ni)                                           \
      bfr[ni] = *(const bfx8*)&CURB[g][wn + ni * 16 + r16][0];               \
    _Pragma("unroll")                                                        \
    for (int mi = 0; mi < 4; ++mi)                                           \
      _Pragma("unroll")                                                      \
      for (int ni = 0; ni < 4; ++ni)                                         \
        acc[mi][ni] = mfma16(af[mi], bfr[ni], acc[mi][ni]);                  \
  }

  stageTo(&As0[0][0][0], &Bs0[0][0][0], 0);
  stageTo(&As1[0][0][0], &Bs1[0][0][0], 1);
  for (int t = 0; t < nk; t += 3) {
    GPT_PHASE(As0, Bs0, As2, Bs2, t);
    GPT_PHASE(As1, Bs1, As0, Bs0, t + 1);
    GPT_PHASE(As2, Bs2, As1, Bs1, t + 2);
  }
#undef GPT_PHASE

  const bool hasBias = flags & 1, hasRes = flags & 2;
  const bool doGelu  = flags & 4, outBf  = flags & 8;
  float* outF = (float*)outp + (size_t)blockIdx.z * ((size_t)M * N);
  bh_t*  outB = (bh_t*)outp;
  #pragma unroll
  for (int mi = 0; mi < 4; ++mi) {
    #pragma unroll
    for (int ni = 0; ni < 4; ++ni) {
      const int col = n0 + wn + ni * 16 + r16;
      if (col >= N) continue;
      const int rowb = m0 + wm + mi * 16 + 4 * g;
      const float bv = hasBias ? bias[col] : 0.0f;
      #pragma unroll
      for (int rr = 0; rr < 4; ++rr) {
        const size_t idx = (size_t)(rowb + rr) * N + col;
        float v = acc[mi][ni][rr] + bv;
        if (doGelu) v = 0.5f * v * (1.0f + erff(v * 0.70710678118654752f));
        if (hasRes) v += resid[idx];
        if (outBf) outB[idx] = (bh_t)v; else outF[idx] = v;
      }
    }
  }
}

// ---------------------------------------------------------------------------
// split-K reduce: x[idx] = resid(x)[idx] + bias[col] + sum_s part[s][idx]
// ---------------------------------------------------------------------------
__global__ __launch_bounds__(256) void sk_reduce(
    const float* __restrict__ part, const float* __restrict__ bias,
    float* __restrict__ x, int N, int S)
{
  const size_t i4 = ((size_t)blockIdx.x * 256 + threadIdx.x) * 4;
  const size_t stride = (size_t)MROWS * N;
  float4 a = *(const float4*)(part + i4);
  for (int s = 1; s < S; ++s) {
    const float4 p = *(const float4*)(part + s * stride + i4);
    a.x += p.x; a.y += p.y; a.z += p.z; a.w += p.w;
  }
  const int col = (int)(i4 % N);
  const float4 bv = *(const float4*)(bias + col);
  const float4 rv = *(const float4*)(x + i4);
  a.x += bv.x + rv.x; a.y += bv.y + rv.y; a.z += bv.z + rv.z; a.w += bv.w + rv.w;
  *(float4*)(x + i4) = a;
}

// ---------------------------------------------------------------------------
// Flash attention, causal. One wave per (b, h, 16 q-rows).
// ---------------------------------------------------------------------------
__global__ __launch_bounds__(256) void attn_fwd(
    const bh_t* __restrict__ qkv, const bh_t* __restrict__ vT,
    bh_t* __restrict__ outb)
{
  __shared__ bh_t P[4][16][56];
  const int wave = threadIdx.x >> 6, lane = threadIdx.x & 63;
  const int g = lane >> 4, r16 = lane & 15;
  const int gw = blockIdx.x * 4 + wave;
  const int qblk = gw & 63;
  const int bh = gw >> 6;
  const int h = bh % NHEAD, b = bh / NHEAD;
  const int qbase = qblk * 16;
  const int qidx = qbase + r16;

  const bh_t* qp = qkv + (size_t)(b * TSEQ + qbase + r16) * (3 * CDIM) + h * HDIM + 8 * g;
  const bfx8 qf0 = *(const bfx8*)qp;
  const bfx8 qf1 = *(const bfx8*)(qp + 32);

  fx4 o[4] = {};
  float m = -INFINITY, l = 0.0f;
  const int ntiles = qblk / 2 + 1;

  for (int t = 0; t < ntiles; ++t) {
    const int kv0 = t * 32;
    const bh_t* kp = qkv + (size_t)(b * TSEQ + kv0 + r16) * (3 * CDIM) + CDIM + h * HDIM + 8 * g;
    const bfx8 ka0 = *(const bfx8*)kp;
    const bfx8 ka1 = *(const bfx8*)(kp + 32);
    const bfx8 kb0 = *(const bfx8*)(kp + 16 * (3 * CDIM));
    const bfx8 kb1 = *(const bfx8*)(kp + 16 * (3 * CDIM) + 32);
    fx4 s0 = {}, s1 = {};
    s0 = mfma16(ka0, qf0, s0); s0 = mfma16(ka1, qf1, s0);   // S^T: [kv][q]
    s1 = mfma16(kb0, qf0, s1); s1 = mfma16(kb1, qf1, s1);

    float mx = -INFINITY;
    float sv0[4], sv1[4];
    #pragma unroll
    for (int rr = 0; rr < 4; ++rr) {
      const int kva = kv0 + 4 * g + rr;
      const int kvb = kva + 16;
      sv0[rr] = (kva <= qidx) ? s0[rr] * 0.125f : -INFINITY;
      sv1[rr] = (kvb <= qidx) ? s1[rr] * 0.125f : -INFINITY;
      mx = fmaxf(mx, fmaxf(sv0[rr], sv1[rr]));
    }
    mx = fmaxf(mx, __shfl_xor(mx, 16));
    mx = fmaxf(mx, __shfl_xor(mx, 32));
    const float mnew = fmaxf(m, mx);
    const float corr = __expf(m - mnew);

    float ps = 0.0f;
    float pv0[4], pv1[4];
    #pragma unroll
    for (int rr = 0; rr < 4; ++rr) {
      pv0[rr] = __expf(sv0[rr] - mnew);
      pv1[rr] = __expf(sv1[rr] - mnew);
      ps += pv0[rr] + pv1[rr];
    }
    ps += __shfl_xor(ps, 16);
    ps += __shfl_xor(ps, 32);
    l = l * corr + ps;
    m = mnew;

    #pragma unroll
    for (int rr = 0; rr < 4; ++rr) {
      const float cr = __shfl(corr, 4 * g + rr);
      o[0][rr] *= cr; o[1][rr] *= cr; o[2][rr] *= cr; o[3][rr] *= cr;
    }

    bfx4 w0, w1;
    #pragma unroll
    for (int rr = 0; rr < 4; ++rr) { w0[rr] = (bh_t)pv0[rr]; w1[rr] = (bh_t)pv1[rr]; }
    *(bfx4*)&P[wave][r16][4 * g]      = w0;
    *(bfx4*)&P[wave][r16][16 + 4 * g] = w1;
    __builtin_amdgcn_wave_barrier();
    const bfx8 pf = *(const bfx8*)&P[wave][r16][8 * g];

    #pragma unroll
    for (int fi = 0; fi < 4; ++fi) {
      const bh_t* vp = vT + (size_t)(bh * HDIM + fi * 16 + r16) * TSEQ + kv0 + 8 * g;
      const bfx8 vf = *(const bfx8*)vp;
      o[fi] = mfma16(pf, vf, o[fi]);
    }
  }

  #pragma unroll
  for (int rr = 0; rr < 4; ++rr) {
    const float lr = __shfl(l, 4 * g + rr);
    const float inv = 1.0f / lr;
    const int trow = b * TSEQ + qbase + 4 * g + rr;
    #pragma unroll
    for (int fi = 0; fi < 4; ++fi)
      outb[(size_t)trow * CDIM + h * HDIM + fi * 16 + r16] = (bh_t)(o[fi][rr] * inv);
  }
}

// ---------------------------------------------------------------------------
// LayerNorm: f32 in -> bf16 out. One wave per row.
// ---------------------------------------------------------------------------
__global__ __launch_bounds__(256) void ln_fwd(
    const float* __restrict__ x, const float* __restrict__ w,
    const float* __restrict__ bb, bh_t* __restrict__ out)
{
  const int wave = threadIdx.x >> 6, lane = threadIdx.x & 63;
  const int row = blockIdx.x * 4 + wave;
  const float* xr = x + (size_t)row * CDIM;
  const int off = lane * 4;
  const float4 v0 = *(const float4*)(xr + off);
  const float4 v1 = *(const float4*)(xr + 256 + off);
  const float4 v2 = *(const float4*)(xr + 512 + off);
  float s  = v0.x + v0.y + v0.z + v0.w + v1.x + v1.y + v1.z + v1.w
           + v2.x + v2.y + v2.z + v2.w;
  float ss = v0.x*v0.x + v0.y*v0.y + v0.z*v0.z + v0.w*v0.w
           + v1.x*v1.x + v1.y*v1.y + v1.z*v1.z + v1.w*v1.w
           + v2.x*v2.x + v2.y*v2.y + v2.z*v2.z + v2.w*v2.w;
  #pragma unroll
  for (int d = 1; d < 64; d <<= 1) { s += __shfl_xor(s, d); ss += __shfl_xor(ss, d); }
  const float mean = s * (1.0f / 768.0f);
  const float inv = rsqrtf(ss * (1.0f / 768.0f) - mean * mean + 1e-5f);
  bh_t* orow = out + (size_t)row * CDIM;

  const float4 w0 = *(const float4*)(w + off),  b0 = *(const float4*)(bb + off);
  const float4 w1 = *(const float4*)(w + 256 + off), b1 = *(const float4*)(bb + 256 + off);
  const float4 w2 = *(const float4*)(w + 512 + off), b2 = *(const float4*)(bb + 512 + off);
  bfx4 o;
  o[0] = (bh_t)((v0.x - mean) * inv * w0.x + b0.x);
  o[1] = (bh_t)((v0.y - mean) * inv * w0.y + b0.y);
  o[2] = (bh_t)((v0.z - mean) * inv * w0.z + b0.z);
  o[3] = (bh_t)((v0.w - mean) * inv * w0.w + b0.w);
  *(bfx4*)(orow + off) = o;
  o[0] = (bh_t)((v1.x - mean) * inv * w1.x + b1.x);
  o[1] = (bh_t)((v1.y - mean) * inv * w1.y + b1.y);
  o[2] = (bh_t)((v1.z - mean) * inv * w1.z + b1.z);
  o[3] = (bh_t)((v1.w - mean) * inv * w1.w + b1.w);
  *(bfx4*)(orow + 256 + off) = o;
  o[0] = (bh_t)((v2.x - mean) * inv * w2.x + b2.x);
  o[1] = (bh_t)((v2.y - mean) * inv * w2.y + b2.y);
  o[2] = (bh_t)((v2.z - mean) * inv * w2.z + b2.z);
  o[3] = (bh_t)((v2.w - mean) * inv * w2.w + b2.w);
  *(bfx4*)(orow + 512 + off) = o;
}

// ---------------------------------------------------------------------------
__global__ void embed_k(const int* __restrict__ ids, const float* __restrict__ tok,
                        const float* __restrict__ pos, float* __restrict__ x)
{
  const int bt = blockIdx.x;
  const int t = bt & (TSEQ - 1);
  const int id = ids[bt];
  const float* tr = tok + (size_t)id * CDIM;
  const float* pr = pos + (size_t)t * CDIM;
  float* xr = x + (size_t)bt * CDIM;
  for (int j = threadIdx.x; j < CDIM; j += 256) xr[j] = tr[j] + pr[j];
}

// transpose + f32->bf16: in [L][R][Cn] -> out [L][Cn][R]
__global__ void tconv(const float* __restrict__ in, bh_t* __restrict__ out, int R, int Cn)
{
  __shared__ float tile[32][33];
  const size_t msz = (size_t)R * Cn;
  in  += msz * blockIdx.z;
  out += msz * blockIdx.z;
  const int tx = threadIdx.x & 31, ty = threadIdx.x >> 5;
  const int c0 = blockIdx.x * 32, r0 = blockIdx.y * 32;
  #pragma unroll
  for (int i = 0; i < 32; i += 8)
    tile[ty + i][tx] = in[(size_t)(r0 + ty + i) * Cn + c0 + tx];
  __syncthreads();
  #pragma unroll
  for (int i = 0; i < 32; i += 8)
    out[(size_t)(c0 + ty + i) * R + r0 + tx] = (bh_t)tile[tx][ty + i];
}

// tok_emb f32 [V][C] -> bf16 [VPAD][C], zero-padded rows
__global__ void embconv(const float* __restrict__ in, bh_t* __restrict__ out)
{
  const size_t i4 = ((size_t)blockIdx.x * 256 + threadIdx.x) * 4;
  const size_t vlim = (size_t)VOCAB * CDIM;
  float4 f = make_float4(0.f, 0.f, 0.f, 0.f);
  if (i4 < vlim) f = *(const float4*)(in + i4);
  bfx4 o;
  o[0] = (bh_t)f.x; o[1] = (bh_t)f.y; o[2] = (bh_t)f.z; o[3] = (bh_t)f.w;
  *(bfx4*)(out + i4) = o;
}

// V slice of qkv -> vT[bh*64 + d][t]
__global__ void vtrans(const bh_t* __restrict__ qkv, bh_t* __restrict__ vT)
{
  __shared__ bh_t tile[32][34];
  const int bh = blockIdx.z;
  const int b = bh / NHEAD, h = bh % NHEAD;
  const int d0 = blockIdx.x * 32, t0 = blockIdx.y * 32;
  const int tx = threadIdx.x & 31, ty = threadIdx.x >> 5;
  #pragma unroll
  for (int i = 0; i < 32; i += 8)
    tile[ty + i][tx] = qkv[(size_t)(b * TSEQ + t0 + ty + i) * (3 * CDIM) + 2 * CDIM + h * HDIM + d0 + tx];
  __syncthreads();
  #pragma unroll
  for (int i = 0; i < 32; i += 8)
    vT[(size_t)(bh * HDIM + d0 + ty + i) * TSEQ + t0 + tx] = tile[tx][ty + i];
}

// ---------------------------------------------------------------------------
extern "C" void kernel_launch(void* const* d_in, const int* in_sizes, int n_in,
                              void* d_out, int out_size, void* d_ws, size_t ws_size,
                              hipStream_t stream)
{
  (void)in_sizes; (void)n_in; (void)out_size; (void)ws_size;
  const int*   ids    = (const int*)d_in[0];
  const float* tok    = (const float*)d_in[1];
  const float* pos    = (const float*)d_in[2];
  const float* qkv_w  = (const float*)d_in[3];
  const float* qkv_b  = (const float*)d_in[4];
  const float* proj_w = (const float*)d_in[5];
  const float* proj_b = (const float*)d_in[6];
  const float* ln1_w  = (const float*)d_in[7];
  const float* ln1_b  = (const float*)d_in[8];
  const float* ln2_w  = (const float*)d_in[9];
  const float* ln2_b  = (const float*)d_in[10];
  const float* fc1_w  = (const float*)d_in[11];
  const float* fc1_b  = (const float*)d_in[12];
  const float* fc2_w  = (const float*)d_in[13];
  const float* fc2_b  = (const float*)d_in[14];
  const float* lnf_w  = (const float*)d_in[15];
  const float* lnf_b  = (const float*)d_in[16];

  // ---- scratch in ws (activations + embT), ~153 MB
  char* wp = (char*)d_ws;
  auto carve = [&](size_t bytes) { char* p = wp; wp += (bytes + 255) & ~(size_t)255; return p; };
  float* x     = (float*)carve((size_t)MROWS * CDIM * 4);
  bh_t*  hbuf  = (bh_t*)carve((size_t)MROWS * CDIM * 2);
  bh_t*  qkvb  = (bh_t*)carve((size_t)MROWS * 3 * CDIM * 2);
  bh_t*  vT    = (bh_t*)carve((size_t)48 * HDIM * TSEQ * 2);
  bh_t*  attno = (bh_t*)carve((size_t)MROWS * CDIM * 2);
  bh_t*  mlp1  = (bh_t*)carve((size_t)MROWS * 3072 * 2);
  bh_t*  embT  = (bh_t*)carve((size_t)VPAD * CDIM * 2);

  // ---- staged in d_out (dead before lm_head overwrites it), ~270 MB of 823
  char* op = (char*)d_out;
  auto carveO = [&](size_t bytes) { char* p = op; op += (bytes + 255) & ~(size_t)255; return p; };
  bh_t* qkvwT  = (bh_t*)carveO((size_t)NLAYER * 3 * CDIM * CDIM * 2);
  bh_t* projwT = (bh_t*)carveO((size_t)NLAYER * CDIM * CDIM * 2);
  bh_t* fc1wT  = (bh_t*)carveO((size_t)NLAYER * 3072 * CDIM * 2);
  bh_t* fc2wT  = (bh_t*)carveO((size_t)NLAYER * CDIM * 3072 * 2);
  float* skpart = (float*)carveO((size_t)4 * MROWS * CDIM * 4);   // split-K partials

  tconv<<<dim3(2304 / 32, 768 / 32, NLAYER), 256, 0, stream>>>(qkv_w, qkvwT, 768, 2304);
  tconv<<<dim3(768 / 32, 768 / 32, NLAYER), 256, 0, stream>>>(proj_w, projwT, 768, 768);
  tconv<<<dim3(3072 / 32, 768 / 32, NLAYER), 256, 0, stream>>>(fc1_w, fc1wT, 768, 3072);
  tconv<<<dim3(768 / 32, 3072 / 32, NLAYER), 256, 0, stream>>>(fc2_w, fc2wT, 3072, 768);
  embconv<<<(VPAD * CDIM / 4) / 256, 256, 0, stream>>>(tok, embT);
  embed_k<<<MROWS, 256, 0, stream>>>(ids, tok, pos, x);

  for (int l = 0; l < NLAYER; ++l) {
    ln_fwd<<<MROWS / 4, 256, 0, stream>>>(x, ln1_w + l * CDIM, ln1_b + l * CDIM, hbuf);
    gemm_bt<<<dim3(32, 18), 256, 0, stream>>>(hbuf, qkvwT + (size_t)l * 3 * CDIM * CDIM,
        qkv_b + l * 3 * CDIM, nullptr, qkvb, MROWS, 3 * CDIM, CDIM, CDIM, 1 | 8);
    vtrans<<<dim3(2, 32, 48), 256, 0, stream>>>(qkvb, vT);
    attn_fwd<<<768, 256, 0, stream>>>(qkvb, vT, attno);
    // proj: split-K x4 in one dispatch (grid z), K_eff=192 (nk=6), 768 blocks
    gemm_bt<<<dim3(32, 6, 4), 256, 0, stream>>>(attno,
        projwT + (size_t)l * CDIM * CDIM, nullptr, nullptr,
        skpart, MROWS, CDIM, 192, CDIM, 0);
    sk_reduce<<<(MROWS * CDIM / 4) / 256, 256, 0, stream>>>(skpart, proj_b + l * CDIM, x, CDIM, 4);
    ln_fwd<<<MROWS / 4, 256, 0, stream>>>(x, ln2_w + l * CDIM, ln2_b + l * CDIM, hbuf);
    gemm_bt<<<dim3(32, 24), 256, 0, stream>>>(hbuf, fc1wT + (size_t)l * 3072 * CDIM,
        fc1_b + l * 3072, nullptr, mlp1, MROWS, 3072, CDIM, CDIM, 1 | 4 | 8);
    // fc2: split-K x4 in one dispatch, K_eff=768 (nk=24), 768 blocks
    gemm_bt<<<dim3(32, 6, 4), 256, 0, stream>>>(mlp1,
        fc2wT + (size_t)l * CDIM * 3072, nullptr, nullptr,
        skpart, MROWS, CDIM, 768, 3072, 0);
    sk_reduce<<<(MROWS * CDIM / 4) / 256, 256, 0, stream>>>(skpart, fc2_b + l * CDIM, x, CDIM, 4);
  }
  ln_fwd<<<MROWS / 4, 256, 0, stream>>>(x, lnf_w, lnf_b, hbuf);
  gemm_bt<<<dim3(32, VPAD / 128), 256, 0, stream>>>(hbuf, embT, nullptr, nullptr,
      (float*)d_out, MROWS, VOCAB, CDIM, CDIM, 0);
}

// Round 6
// 4393.876 us; speedup vs baseline: 1.3641x; 1.0617x over previous
//
#include <hip/hip_runtime.h>
#include <hip/hip_bf16.h>

// GPT-2 small forward on gfx950. bf16 MFMA GEMMs (f32 accum), flash attention.
// R6: lm_head -> 256x256 8-wave kernel ported from the m201 8-phase template:
//     st_16x32 LDS swizzle (pre-swizzled gload_lds source + swizzled ds_read),
//     1 half-tile staged per phase, counted vmcnt(2) once per K-tile (never 0
//     mid-loop), 2 barriers/tile, setprio around MFMA. Layer GEMMs keep R5.

typedef __bf16 bh_t;
typedef __bf16 bfx4 __attribute__((ext_vector_type(4)));
typedef __bf16 bfx8 __attribute__((ext_vector_type(8)));
typedef float  fx4  __attribute__((ext_vector_type(4)));

#define CDIM 768
#define TSEQ 1024
#define NHEAD 12
#define HDIM 64
#define NLAYER 12
#define MROWS 4096          // B*T
#define VOCAB 50257
#define VPAD  50432         // 197 * 256

__device__ __forceinline__ void gload_lds16(const void* g, void* l) {
  __builtin_amdgcn_global_load_lds(
      (const __attribute__((address_space(1))) void*)g,
      (__attribute__((address_space(3))) void*)l, 16, 0, 0);
}

__device__ __forceinline__ fx4 mfma16(bfx8 a, bfx8 b, fx4 c) {
  return __builtin_amdgcn_mfma_f32_16x16x32_bf16(a, b, c, 0, 0, 0);
}

// ---------------------------------------------------------------------------
// lm_head GEMM: C[M,N] = A[M,K] @ B^T[Npad,K], 256x256 tile, BK=64, 8 waves.
// K = 768 (12 K-tiles). 128 KiB LDS, double-buffered, st_16x32 swizzle.
// ---------------------------------------------------------------------------
__global__ __launch_bounds__(512, 2) void gemm_lm256(
    const bh_t* __restrict__ A, const bh_t* __restrict__ B,
    float* __restrict__ C, int M, int N, int K)
{
  __shared__ bh_t LA0[2][128][64], LB0[2][128][64];   // buf0: [half][row][k]
  __shared__ bh_t LA1[2][128][64], LB1[2][128][64];   // buf1
  const int tid = threadIdx.x;
  const int wid = tid >> 6, lane = tid & 63;
  const int g = lane >> 4, r16 = lane & 15;
  const int g2 = g ^ (((r16 >> 2) & 1) << 1);         // st_16x32 read swizzle
  const int wr = wid >> 2, wc = wid & 3;              // 2M x 4N waves
  const int m0 = blockIdx.x * 256, n0 = blockIdx.y * 256;

  const bh_t* Ab0 = A + (size_t)m0 * K;               // A rows m0..+127
  const bh_t* Ab1 = Ab0 + (size_t)128 * K;            // A rows +128..+255
  const bh_t* Bb0 = B + (size_t)n0 * K;
  const bh_t* Bb1 = Bb0 + (size_t)128 * K;

  fx4 acc[8][4] = {};

  // stage one 128x64 half-tile (16 KB): 2 gloads/wave, source pre-swizzled
  // with the involution idx ^= ((idx>>5)&1)<<1 (byte form: L ^= ((L>>9)&1)<<5)
  auto stageHalf = [&](bh_t* dst, const bh_t* src, int t) {
    const int k0 = t << 6;
    #pragma unroll
    for (int j = 0; j < 2; ++j) {
      const int idx = j * 512 + tid;
      const int sidx = idx ^ (((idx >> 5) & 1) << 1);
      gload_lds16(src + (size_t)(sidx >> 3) * K + k0 + (sidx & 7) * 8,
                  dst + (size_t)idx * 8);
    }
  };

  const bh_t* aBase;  // set per-tile below via macro args
  (void)aBase;

#define LM_TILE(CA, CB, NA, NB, T)                                            \
  {                                                                           \
    const bh_t* ca = &CA[wr][0][0];                                           \
    const bh_t* cb = &CB[wc >> 1][0][0] + (size_t)((wc & 1) * 64) * 64;       \
    bfx8 a0[4], b0[4], b1[4];                                                 \
    /* ph1: A mi0-3 ks0 + B ks0, 16 MFMA */                                   \
    _Pragma("unroll")                                                         \
    for (int ni = 0; ni < 4; ++ni)                                            \
      b0[ni] = *(const bfx8*)(cb + (size_t)(ni * 16 + r16) * 64 + g2 * 8);    \
    _Pragma("unroll")                                                         \
    for (int mi = 0; mi < 4; ++mi)                                            \
      a0[mi] = *(const bfx8*)(ca + (size_t)(mi * 16 + r16) * 64 + g2 * 8);    \
    __builtin_amdgcn_s_setprio(1);                                            \
    _Pragma("unroll")                                                         \
    for (int mi = 0; mi < 4; ++mi)                                            \
      _Pragma("unroll")                                                       \
      for (int ni = 0; ni < 4; ++ni)                                          \
        acc[mi][ni] = mfma16(a0[mi], b0[ni], acc[mi][ni]);                    \
    __builtin_amdgcn_s_setprio(0);                                            \
    /* ph2: stage (T+1).H1; A mi4-7 ks0 */                                    \
    if ((T) + 1 < 12) stageHalf(&NA[1][0][0], Ab1, (T) + 1);                  \
    _Pragma("unroll")                                                         \
    for (int mi = 0; mi < 4; ++mi)                                            \
      a0[mi] = *(const bfx8*)(ca + (size_t)(64 + mi * 16 + r16) * 64 + g2 * 8);\
    __builtin_amdgcn_s_setprio(1);                                            \
    _Pragma("unroll")                                                         \
    for (int mi = 0; mi < 4; ++mi)                                            \
      _Pragma("unroll")                                                       \
      for (int ni = 0; ni < 4; ++ni)                                          \
        acc[4 + mi][ni] = mfma16(a0[mi], b0[ni], acc[4 + mi][ni]);            \
    __builtin_amdgcn_s_setprio(0);                                            \
    /* ph3: stage (T+1).H2; A mi0-3 ks1 + B ks1 */                            \
    if ((T) + 1 < 12) stageHalf(&NB[0][0][0], Bb0, (T) + 1);                  \
    _Pragma("unroll")                                                         \
    for (int ni = 0; ni < 4; ++ni)                                            \
      b1[ni] = *(const bfx8*)(cb + (size_t)(ni * 16 + r16) * 64 + 32 + g2 * 8);\
    _Pragma("unroll")                                                         \
    for (int mi = 0; mi < 4; ++mi)                                            \
      a0[mi] = *(const bfx8*)(ca + (size_t)(mi * 16 + r16) * 64 + 32 + g2 * 8);\
    __builtin_amdgcn_s_setprio(1);                                            \
    _Pragma("unroll")                                                         \
    for (int mi = 0; mi < 4; ++mi)                                            \
      _Pragma("unroll")                                                       \
      for (int ni = 0; ni < 4; ++ni)                                          \
        acc[mi][ni] = mfma16(a0[mi], b1[ni], acc[mi][ni]);                    \
    __builtin_amdgcn_s_setprio(0);                                            \
    /* ph4: stage (T+1).H3; A mi4-7 ks1 */                                    \
    if ((T) + 1 < 12) stageHalf(&NB[1][0][0], Bb1, (T) + 1);                  \
    _Pragma("unroll")                                                         \
    for (int mi = 0; mi < 4; ++mi)                                            \
      a0[mi] = *(const bfx8*)(ca + (size_t)(64 + mi * 16 + r16) * 64 + 32 + g2 * 8);\
    __builtin_amdgcn_s_setprio(1);                                            \
    _Pragma("unroll")                                                         \
    for (int mi = 0; mi < 4; ++mi)                                            \
      _Pragma("unroll")                                                       \
      for (int ni = 0; ni < 4; ++ni)                                          \
        acc[4 + mi][ni] = mfma16(a0[mi], b1[ni], acc[4 + mi][ni]);            \
    __builtin_amdgcn_s_setprio(0);                                            \
    /* boundary: reads of C* done -> barrier; stage (T+2).H0 into C*;        \
       counted vmcnt retires tile T+1's 8 loads; barrier; fence */            \
    asm volatile("s_waitcnt lgkmcnt(0)" ::: "memory");                        \
    __builtin_amdgcn_s_barrier();                                             \
    if ((T) + 2 < 12) {                                                       \
      stageHalf(&CA[0][0][0], Ab0, (T) + 2);                                  \
      asm volatile("s_waitcnt vmcnt(2)" ::: "memory");                        \
    } else if ((T) + 1 < 12) {                                                \
      asm volatile("s_waitcnt vmcnt(0)" ::: "memory");                        \
    }                                                                         \
    __builtin_amdgcn_s_barrier();                                             \
    asm volatile("" ::: "memory");                                            \
  }

  // prologue: tile 0 fully + tile 1.H0; per-wave outstanding 10 -> keep 2
  stageHalf(&LA0[0][0][0], Ab0, 0);
  stageHalf(&LA0[1][0][0], Ab1, 0);
  stageHalf(&LB0[0][0][0], Bb0, 0);
  stageHalf(&LB0[1][0][0], Bb1, 0);
  stageHalf(&LA1[0][0][0], Ab0, 1);
  asm volatile("s_waitcnt vmcnt(2)" ::: "memory");
  __builtin_amdgcn_s_barrier();
  asm volatile("" ::: "memory");

  for (int t = 0; t < 12; t += 2) {
    LM_TILE(LA0, LB0, LA1, LB1, t);
    LM_TILE(LA1, LB1, LA0, LB0, t + 1);
  }
#undef LM_TILE

  #pragma unroll
  for (int mi = 0; mi < 8; ++mi) {
    const int rowb = m0 + wr * 128 + mi * 16 + 4 * g;
    #pragma unroll
    for (int ni = 0; ni < 4; ++ni) {
      const int col = n0 + wc * 64 + ni * 16 + r16;
      if (col >= N) continue;
      #pragma unroll
      for (int rr = 0; rr < 4; ++rr)
        C[(size_t)(rowb + rr) * N + col] = acc[mi][ni][rr];
    }
  }
}

// ---------------------------------------------------------------------------
// GEMM: C[M,N] = A[M,K'] @ B^T[N,K']  (+bias, +gelu, +residual)
// 128x128 tile, BK=32, 4 waves (2x2), 3-deep LDS pipeline (R5).
// ---------------------------------------------------------------------------
__global__ __launch_bounds__(256, 3) void gemm_bt(
    const bh_t* __restrict__ A, const bh_t* __restrict__ B,
    const float* __restrict__ bias, const float* __restrict__ resid,
    void* __restrict__ outp, int M, int N, int K, int lda, int flags)
{
  __shared__ bh_t As0[4][128][8], Bs0[4][128][8];   // [k-block][row][8 k]
  __shared__ bh_t As1[4][128][8], Bs1[4][128][8];
  __shared__ bh_t As2[4][128][8], Bs2[4][128][8];
  const int tid  = threadIdx.x;
  const int wave = tid >> 6, lane = tid & 63;
  const int g = lane >> 4, r16 = lane & 15;
  const int m0 = blockIdx.x * 128, n0 = blockIdx.y * 128;
  const int wm = (wave >> 1) * 64, wn = (wave & 1) * 64;

  const bh_t* Ab = A;
  const bh_t* Bb = B;
  if (gridDim.z > 1) {   // split-K: advance along k
    Ab += (size_t)blockIdx.z * K;
    Bb += (size_t)blockIdx.z * K;
  }
  Ab += (size_t)m0 * lda;
  Bb += (size_t)n0 * lda;

  const int row0 = tid & 127, kb0 = tid >> 7;
  const int row1 = row0, kb1 = kb0 + 2;            // tid+256 pattern

  fx4 acc[4][4] = {};
  const int nk = K >> 5;

  auto stageTo = [&](bh_t* AsF, bh_t* BsF, int t) {
    const int k0 = t << 5;
    gload_lds16(Ab + (size_t)row0 * lda + k0 + kb0 * 8, AsF + (size_t)(wave * 64) * 8);
    gload_lds16(Ab + (size_t)row1 * lda + k0 + kb1 * 8, AsF + (size_t)(256 + wave * 64) * 8);
    gload_lds16(Bb + (size_t)row0 * lda + k0 + kb0 * 8, BsF + (size_t)(wave * 64) * 8);
    gload_lds16(Bb + (size_t)row1 * lda + k0 + kb1 * 8, BsF + (size_t)(256 + wave * 64) * 8);
  };

#define GPT_PHASE(CURA, CURB, NXA, NXB, T)                                   \
  {                                                                          \
    if ((T) + 1 < nk) { asm volatile("s_waitcnt vmcnt(4)" ::: "memory"); }   \
    else              { asm volatile("s_waitcnt vmcnt(0)" ::: "memory"); }   \
    __builtin_amdgcn_s_barrier();                                            \
    asm volatile("" ::: "memory");                                           \
    if ((T) + 2 < nk) stageTo(&NXA[0][0][0], &NXB[0][0][0], (T) + 2);        \
    bfx8 af[4], bfr[4];                                                      \
    _Pragma("unroll")                                                        \
    for (int mi = 0; mi < 4; ++mi)                                           \
      af[mi] = *(const bfx8*)&CURA[g][wm + mi * 16 + r16][0];                \
    _Pragma("unroll")                                                        \
    for (int ni = 0; ni < 4; ++ni)                                           \
      bfr[ni] = *(const bfx8*)&CURB[g][wn + ni * 16 + r16][0];               \
    _Pragma("unroll")                                                        \
    for (int mi = 0; mi < 4; ++mi)                                           \
      _Pragma("unroll")                                                      \
      for (int ni = 0; ni < 4; ++ni)                                         \
        acc[mi][ni] = mfma16(af[mi], bfr[ni], acc[mi][ni]);                  \
  }

  stageTo(&As0[0][0][0], &Bs0[0][0][0], 0);
  stageTo(&As1[0][0][0], &Bs1[0][0][0], 1);
  for (int t = 0; t < nk; t += 3) {
    GPT_PHASE(As0, Bs0, As2, Bs2, t);
    GPT_PHASE(As1, Bs1, As0, Bs0, t + 1);
    GPT_PHASE(As2, Bs2, As1, Bs1, t + 2);
  }
#undef GPT_PHASE

  const bool hasBias = flags & 1, hasRes = flags & 2;
  const bool doGelu  = flags & 4, outBf  = flags & 8;
  float* outF = (float*)outp + (size_t)blockIdx.z * ((size_t)M * N);
  bh_t*  outB = (bh_t*)outp;
  #pragma unroll
  for (int mi = 0; mi < 4; ++mi) {
    #pragma unroll
    for (int ni = 0; ni < 4; ++ni) {
      const int col = n0 + wn + ni * 16 + r16;
      if (col >= N) continue;
      const int rowb = m0 + wm + mi * 16 + 4 * g;
      const float bv = hasBias ? bias[col] : 0.0f;
      #pragma unroll
      for (int rr = 0; rr < 4; ++rr) {
        const size_t idx = (size_t)(rowb + rr) * N + col;
        float v = acc[mi][ni][rr] + bv;
        if (doGelu) v = 0.5f * v * (1.0f + erff(v * 0.70710678118654752f));
        if (hasRes) v += resid[idx];
        if (outBf) outB[idx] = (bh_t)v; else outF[idx] = v;
      }
    }
  }
}

// ---------------------------------------------------------------------------
// split-K reduce: x[idx] = resid(x)[idx] + bias[col] + sum_s part[s][idx]
// ---------------------------------------------------------------------------
__global__ __launch_bounds__(256) void sk_reduce(
    const float* __restrict__ part, const float* __restrict__ bias,
    float* __restrict__ x, int N, int S)
{
  const size_t i4 = ((size_t)blockIdx.x * 256 + threadIdx.x) * 4;
  const size_t stride = (size_t)MROWS * N;
  float4 a = *(const float4*)(part + i4);
  for (int s = 1; s < S; ++s) {
    const float4 p = *(const float4*)(part + s * stride + i4);
    a.x += p.x; a.y += p.y; a.z += p.z; a.w += p.w;
  }
  const int col = (int)(i4 % N);
  const float4 bv = *(const float4*)(bias + col);
  const float4 rv = *(const float4*)(x + i4);
  a.x += bv.x + rv.x; a.y += bv.y + rv.y; a.z += bv.z + rv.z; a.w += bv.w + rv.w;
  *(float4*)(x + i4) = a;
}

// ---------------------------------------------------------------------------
// Flash attention, causal. One wave per (b, h, 16 q-rows).
// ---------------------------------------------------------------------------
__global__ __launch_bounds__(256) void attn_fwd(
    const bh_t* __restrict__ qkv, const bh_t* __restrict__ vT,
    bh_t* __restrict__ outb)
{
  __shared__ bh_t P[4][16][56];
  const int wave = threadIdx.x >> 6, lane = threadIdx.x & 63;
  const int g = lane >> 4, r16 = lane & 15;
  const int gw = blockIdx.x * 4 + wave;
  const int qblk = gw & 63;
  const int bh = gw >> 6;
  const int h = bh % NHEAD, b = bh / NHEAD;
  const int qbase = qblk * 16;
  const int qidx = qbase + r16;

  const bh_t* qp = qkv + (size_t)(b * TSEQ + qbase + r16) * (3 * CDIM) + h * HDIM + 8 * g;
  const bfx8 qf0 = *(const bfx8*)qp;
  const bfx8 qf1 = *(const bfx8*)(qp + 32);

  fx4 o[4] = {};
  float m = -INFINITY, l = 0.0f;
  const int ntiles = qblk / 2 + 1;

  for (int t = 0; t < ntiles; ++t) {
    const int kv0 = t * 32;
    const bh_t* kp = qkv + (size_t)(b * TSEQ + kv0 + r16) * (3 * CDIM) + CDIM + h * HDIM + 8 * g;
    const bfx8 ka0 = *(const bfx8*)kp;
    const bfx8 ka1 = *(const bfx8*)(kp + 32);
    const bfx8 kb0 = *(const bfx8*)(kp + 16 * (3 * CDIM));
    const bfx8 kb1 = *(const bfx8*)(kp + 16 * (3 * CDIM) + 32);
    fx4 s0 = {}, s1 = {};
    s0 = mfma16(ka0, qf0, s0); s0 = mfma16(ka1, qf1, s0);   // S^T: [kv][q]
    s1 = mfma16(kb0, qf0, s1); s1 = mfma16(kb1, qf1, s1);

    float mx = -INFINITY;
    float sv0[4], sv1[4];
    #pragma unroll
    for (int rr = 0; rr < 4; ++rr) {
      const int kva = kv0 + 4 * g + rr;
      const int kvb = kva + 16;
      sv0[rr] = (kva <= qidx) ? s0[rr] * 0.125f : -INFINITY;
      sv1[rr] = (kvb <= qidx) ? s1[rr] * 0.125f : -INFINITY;
      mx = fmaxf(mx, fmaxf(sv0[rr], sv1[rr]));
    }
    mx = fmaxf(mx, __shfl_xor(mx, 16));
    mx = fmaxf(mx, __shfl_xor(mx, 32));
    const float mnew = fmaxf(m, mx);
    const float corr = __expf(m - mnew);

    float ps = 0.0f;
    float pv0[4], pv1[4];
    #pragma unroll
    for (int rr = 0; rr < 4; ++rr) {
      pv0[rr] = __expf(sv0[rr] - mnew);
      pv1[rr] = __expf(sv1[rr] - mnew);
      ps += pv0[rr] + pv1[rr];
    }
    ps += __shfl_xor(ps, 16);
    ps += __shfl_xor(ps, 32);
    l = l * corr + ps;
    m = mnew;

    #pragma unroll
    for (int rr = 0; rr < 4; ++rr) {
      const float cr = __shfl(corr, 4 * g + rr);
      o[0][rr] *= cr; o[1][rr] *= cr; o[2][rr] *= cr; o[3][rr] *= cr;
    }

    bfx4 w0, w1;
    #pragma unroll
    for (int rr = 0; rr < 4; ++rr) { w0[rr] = (bh_t)pv0[rr]; w1[rr] = (bh_t)pv1[rr]; }
    *(bfx4*)&P[wave][r16][4 * g]      = w0;
    *(bfx4*)&P[wave][r16][16 + 4 * g] = w1;
    __builtin_amdgcn_wave_barrier();
    const bfx8 pf = *(const bfx8*)&P[wave][r16][8 * g];

    #pragma unroll
    for (int fi = 0; fi < 4; ++fi) {
      const bh_t* vp = vT + (size_t)(bh * HDIM + fi * 16 + r16) * TSEQ + kv0 + 8 * g;
      const bfx8 vf = *(const bfx8*)vp;
      o[fi] = mfma16(pf, vf, o[fi]);
    }
  }

  #pragma unroll
  for (int rr = 0; rr < 4; ++rr) {
    const float lr = __shfl(l, 4 * g + rr);
    const float inv = 1.0f / lr;
    const int trow = b * TSEQ + qbase + 4 * g + rr;
    #pragma unroll
    for (int fi = 0; fi < 4; ++fi)
      outb[(size_t)trow * CDIM + h * HDIM + fi * 16 + r16] = (bh_t)(o[fi][rr] * inv);
  }
}

// ---------------------------------------------------------------------------
// LayerNorm: f32 in -> bf16 out. One wave per row.
// ---------------------------------------------------------------------------
__global__ __launch_bounds__(256) void ln_fwd(
    const float* __restrict__ x, const float* __restrict__ w,
    const float* __restrict__ bb, bh_t* __restrict__ out)
{
  const int wave = threadIdx.x >> 6, lane = threadIdx.x & 63;
  const int row = blockIdx.x * 4 + wave;
  const float* xr = x + (size_t)row * CDIM;
  const int off = lane * 4;
  const float4 v0 = *(const float4*)(xr + off);
  const float4 v1 = *(const float4*)(xr + 256 + off);
  const float4 v2 = *(const float4*)(xr + 512 + off);
  float s  = v0.x + v0.y + v0.z + v0.w + v1.x + v1.y + v1.z + v1.w
           + v2.x + v2.y + v2.z + v2.w;
  float ss = v0.x*v0.x + v0.y*v0.y + v0.z*v0.z + v0.w*v0.w
           + v1.x*v1.x + v1.y*v1.y + v1.z*v1.z + v1.w*v1.w
           + v2.x*v2.x + v2.y*v2.y + v2.z*v2.z + v2.w*v2.w;
  #pragma unroll
  for (int d = 1; d < 64; d <<= 1) { s += __shfl_xor(s, d); ss += __shfl_xor(ss, d); }
  const float mean = s * (1.0f / 768.0f);
  const float inv = rsqrtf(ss * (1.0f / 768.0f) - mean * mean + 1e-5f);
  bh_t* orow = out + (size_t)row * CDIM;

  const float4 w0 = *(const float4*)(w + off),  b0 = *(const float4*)(bb + off);
  const float4 w1 = *(const float4*)(w + 256 + off), b1 = *(const float4*)(bb + 256 + off);
  const float4 w2 = *(const float4*)(w + 512 + off), b2 = *(const float4*)(bb + 512 + off);
  bfx4 o;
  o[0] = (bh_t)((v0.x - mean) * inv * w0.x + b0.x);
  o[1] = (bh_t)((v0.y - mean) * inv * w0.y + b0.y);
  o[2] = (bh_t)((v0.z - mean) * inv * w0.z + b0.z);
  o[3] = (bh_t)((v0.w - mean) * inv * w0.w + b0.w);
  *(bfx4*)(orow + off) = o;
  o[0] = (bh_t)((v1.x - mean) * inv * w1.x + b1.x);
  o[1] = (bh_t)((v1.y - mean) * inv * w1.y + b1.y);
  o[2] = (bh_t)((v1.z - mean) * inv * w1.z + b1.z);
  o[3] = (bh_t)((v1.w - mean) * inv * w1.w + b1.w);
  *(bfx4*)(orow + 256 + off) = o;
  o[0] = (bh_t)((v2.x - mean) * inv * w2.x + b2.x);
  o[1] = (bh_t)((v2.y - mean) * inv * w2.y + b2.y);
  o[2] = (bh_t)((v2.z - mean) * inv * w2.z + b2.z);
  o[3] = (bh_t)((v2.w - mean) * inv * w2.w + b2.w);
  *(bfx4*)(orow + 512 + off) = o;
}

// ---------------------------------------------------------------------------
__global__ void embed_k(const int* __restrict__ ids, const float* __restrict__ tok,
                        const float* __restrict__ pos, float* __restrict__ x)
{
  const int bt = blockIdx.x;
  const int t = bt & (TSEQ - 1);
  const int id = ids[bt];
  const float* tr = tok + (size_t)id * CDIM;
  const float* pr = pos + (size_t)t * CDIM;
  float* xr = x + (size_t)bt * CDIM;
  for (int j = threadIdx.x; j < CDIM; j += 256) xr[j] = tr[j] + pr[j];
}

// transpose + f32->bf16: in [L][R][Cn] -> out [L][Cn][R]
__global__ void tconv(const float* __restrict__ in, bh_t* __restrict__ out, int R, int Cn)
{
  __shared__ float tile[32][33];
  const size_t msz = (size_t)R * Cn;
  in  += msz * blockIdx.z;
  out += msz * blockIdx.z;
  const int tx = threadIdx.x & 31, ty = threadIdx.x >> 5;
  const int c0 = blockIdx.x * 32, r0 = blockIdx.y * 32;
  #pragma unroll
  for (int i = 0; i < 32; i += 8)
    tile[ty + i][tx] = in[(size_t)(r0 + ty + i) * Cn + c0 + tx];
  __syncthreads();
  #pragma unroll
  for (int i = 0; i < 32; i += 8)
    out[(size_t)(c0 + ty + i) * R + r0 + tx] = (bh_t)tile[tx][ty + i];
}

// tok_emb f32 [V][C] -> bf16 [VPAD][C], zero-padded rows
__global__ void embconv(const float* __restrict__ in, bh_t* __restrict__ out)
{
  const size_t i4 = ((size_t)blockIdx.x * 256 + threadIdx.x) * 4;
  if (i4 >= (size_t)VPAD * CDIM) return;
  const size_t vlim = (size_t)VOCAB * CDIM;
  float4 f = make_float4(0.f, 0.f, 0.f, 0.f);
  if (i4 < vlim) f = *(const float4*)(in + i4);
  bfx4 o;
  o[0] = (bh_t)f.x; o[1] = (bh_t)f.y; o[2] = (bh_t)f.z; o[3] = (bh_t)f.w;
  *(bfx4*)(out + i4) = o;
}

// V slice of qkv -> vT[bh*64 + d][t]
__global__ void vtrans(const bh_t* __restrict__ qkv, bh_t* __restrict__ vT)
{
  __shared__ bh_t tile[32][34];
  const int bh = blockIdx.z;
  const int b = bh / NHEAD, h = bh % NHEAD;
  const int d0 = blockIdx.x * 32, t0 = blockIdx.y * 32;
  const int tx = threadIdx.x & 31, ty = threadIdx.x >> 5;
  #pragma unroll
  for (int i = 0; i < 32; i += 8)
    tile[ty + i][tx] = qkv[(size_t)(b * TSEQ + t0 + ty + i) * (3 * CDIM) + 2 * CDIM + h * HDIM + d0 + tx];
  __syncthreads();
  #pragma unroll
  for (int i = 0; i < 32; i += 8)
    vT[(size_t)(bh * HDIM + d0 + ty + i) * TSEQ + t0 + tx] = tile[tx][ty + i];
}

// ---------------------------------------------------------------------------
extern "C" void kernel_launch(void* const* d_in, const int* in_sizes, int n_in,
                              void* d_out, int out_size, void* d_ws, size_t ws_size,
                              hipStream_t stream)
{
  (void)in_sizes; (void)n_in; (void)out_size; (void)ws_size;
  const int*   ids    = (const int*)d_in[0];
  const float* tok    = (const float*)d_in[1];
  const float* pos    = (const float*)d_in[2];
  const float* qkv_w  = (const float*)d_in[3];
  const float* qkv_b  = (const float*)d_in[4];
  const float* proj_w = (const float*)d_in[5];
  const float* proj_b = (const float*)d_in[6];
  const float* ln1_w  = (const float*)d_in[7];
  const float* ln1_b  = (const float*)d_in[8];
  const float* ln2_w  = (const float*)d_in[9];
  const float* ln2_b  = (const float*)d_in[10];
  const float* fc1_w  = (const float*)d_in[11];
  const float* fc1_b  = (const float*)d_in[12];
  const float* fc2_w  = (const float*)d_in[13];
  const float* fc2_b  = (const float*)d_in[14];
  const float* lnf_w  = (const float*)d_in[15];
  const float* lnf_b  = (const float*)d_in[16];

  // ---- scratch in ws (activations + embT), ~153 MB
  char* wp = (char*)d_ws;
  auto carve = [&](size_t bytes) { char* p = wp; wp += (bytes + 255) & ~(size_t)255; return p; };
  float* x     = (float*)carve((size_t)MROWS * CDIM * 4);
  bh_t*  hbuf  = (bh_t*)carve((size_t)MROWS * CDIM * 2);
  bh_t*  qkvb  = (bh_t*)carve((size_t)MROWS * 3 * CDIM * 2);
  bh_t*  vT    = (bh_t*)carve((size_t)48 * HDIM * TSEQ * 2);
  bh_t*  attno = (bh_t*)carve((size_t)MROWS * CDIM * 2);
  bh_t*  mlp1  = (bh_t*)carve((size_t)MROWS * 3072 * 2);
  bh_t*  embT  = (bh_t*)carve((size_t)VPAD * CDIM * 2);

  // ---- staged in d_out (dead before lm_head overwrites it), ~270 MB of 823
  char* op = (char*)d_out;
  auto carveO = [&](size_t bytes) { char* p = op; op += (bytes + 255) & ~(size_t)255; return p; };
  bh_t* qkvwT  = (bh_t*)carveO((size_t)NLAYER * 3 * CDIM * CDIM * 2);
  bh_t* projwT = (bh_t*)carveO((size_t)NLAYER * CDIM * CDIM * 2);
  bh_t* fc1wT  = (bh_t*)carveO((size_t)NLAYER * 3072 * CDIM * 2);
  bh_t* fc2wT  = (bh_t*)carveO((size_t)NLAYER * CDIM * 3072 * 2);
  float* skpart = (float*)carveO((size_t)4 * MROWS * CDIM * 4);   // split-K partials

  tconv<<<dim3(2304 / 32, 768 / 32, NLAYER), 256, 0, stream>>>(qkv_w, qkvwT, 768, 2304);
  tconv<<<dim3(768 / 32, 768 / 32, NLAYER), 256, 0, stream>>>(proj_w, projwT, 768, 768);
  tconv<<<dim3(3072 / 32, 768 / 32, NLAYER), 256, 0, stream>>>(fc1_w, fc1wT, 768, 3072);
  tconv<<<dim3(768 / 32, 3072 / 32, NLAYER), 256, 0, stream>>>(fc2_w, fc2wT, 3072, 768);
  embconv<<<((VPAD * CDIM / 4) + 255) / 256, 256, 0, stream>>>(tok, embT);
  embed_k<<<MROWS, 256, 0, stream>>>(ids, tok, pos, x);

  for (int l = 0; l < NLAYER; ++l) {
    ln_fwd<<<MROWS / 4, 256, 0, stream>>>(x, ln1_w + l * CDIM, ln1_b + l * CDIM, hbuf);
    gemm_bt<<<dim3(32, 18), 256, 0, stream>>>(hbuf, qkvwT + (size_t)l * 3 * CDIM * CDIM,
        qkv_b + l * 3 * CDIM, nullptr, qkvb, MROWS, 3 * CDIM, CDIM, CDIM, 1 | 8);
    vtrans<<<dim3(2, 32, 48), 256, 0, stream>>>(qkvb, vT);
    attn_fwd<<<768, 256, 0, stream>>>(qkvb, vT, attno);
    gemm_bt<<<dim3(32, 6, 4), 256, 0, stream>>>(attno,
        projwT + (size_t)l * CDIM * CDIM, nullptr, nullptr,
        skpart, MROWS, CDIM, 192, CDIM, 0);
    sk_reduce<<<(MROWS * CDIM / 4) / 256, 256, 0, stream>>>(skpart, proj_b + l * CDIM, x, CDIM, 4);
    ln_fwd<<<MROWS / 4, 256, 0, stream>>>(x, ln2_w + l * CDIM, ln2_b + l * CDIM, hbuf);
    gemm_bt<<<dim3(32, 24), 256, 0, stream>>>(hbuf, fc1wT + (size_t)l * 3072 * CDIM,
        fc1_b + l * 3072, nullptr, mlp1, MROWS, 3072, CDIM, CDIM, 1 | 4 | 8);
    gemm_bt<<<dim3(32, 6, 4), 256, 0, stream>>>(mlp1,
        fc2wT + (size_t)l * CDIM * 3072, nullptr, nullptr,
        skpart, MROWS, CDIM, 768, 3072, 0);
    sk_reduce<<<(MROWS * CDIM / 4) / 256, 256, 0, stream>>>(skpart, fc2_b + l * CDIM, x, CDIM, 4);
  }
  ln_fwd<<<MROWS / 4, 256, 0, stream>>>(x, lnf_w, lnf_b, hbuf);
  gemm_lm256<<<dim3(MROWS / 256, VPAD / 256), 512, 0, stream>>>(hbuf, embT,
      (float*)d_out, MROWS, VOCAB, CDIM);
}

// Round 7
// 3941.652 us; speedup vs baseline: 1.5206x; 1.1147x over previous
//
#include <hip/hip_runtime.h>
#include <hip/hip_bf16.h>

// GPT-2 small forward on gfx950. bf16 MFMA GEMMs (f32 accum), flash attention.
// R7: 256x256 8-wave 8-phase kernel (gemm256) gets the CORRECT bank-conflict
//     swizzle (slot ^= row&7 involution on both stage-source and ds_read;
//     R6's 1-bit version left 2.9e7 conflicts). gemm256 generalized with
//     bias/gelu/bf16/split-K epilogue and used for qkv/fc1/fc2/lm_head.
//     sk_reduce fused into LayerNorm (skred_ln). proj keeps 128^2 split-K.

typedef __bf16 bh_t;
typedef __bf16 bfx4 __attribute__((ext_vector_type(4)));
typedef __bf16 bfx8 __attribute__((ext_vector_type(8)));
typedef float  fx4  __attribute__((ext_vector_type(4)));

#define CDIM 768
#define TSEQ 1024
#define NHEAD 12
#define HDIM 64
#define NLAYER 12
#define MROWS 4096          // B*T
#define VOCAB 50257
#define VPAD  50432         // 197 * 256

__device__ __forceinline__ void gload_lds16(const void* g, void* l) {
  __builtin_amdgcn_global_load_lds(
      (const __attribute__((address_space(1))) void*)g,
      (__attribute__((address_space(3))) void*)l, 16, 0, 0);
}

__device__ __forceinline__ fx4 mfma16(bfx8 a, bfx8 b, fx4 c) {
  return __builtin_amdgcn_mfma_f32_16x16x32_bf16(a, b, c, 0, 0, 0);
}

// ---------------------------------------------------------------------------
// 256x256 GEMM: C[M,N] = A[M,K'] @ B^T[N,K'] (+bias,+gelu), 8 waves, BK=64.
// K' = 768 (12 K-tiles) in all uses. 128 KiB LDS double-buffered; LDS tile
// [128][64]bf16 with slot^=row&7 swizzle (conflict-free ds_read_b128).
// blockIdx.z = split-K slice (A,B advance z*K along k; f32 partial out).
// flags: 1=bias, 4=gelu, 8=out bf16. N may be ragged (col guard).
// ---------------------------------------------------------------------------
__global__ __launch_bounds__(512, 1) void gemm256(
    const bh_t* __restrict__ A, const bh_t* __restrict__ B,
    const float* __restrict__ bias, void* __restrict__ outp,
    int M, int N, int K, int lda, int flags)
{
  __shared__ bh_t LA0[2][128][64], LB0[2][128][64];   // buf0: [half][row][k]
  __shared__ bh_t LA1[2][128][64], LB1[2][128][64];   // buf1
  const int tid = threadIdx.x;
  const int wid = tid >> 6, lane = tid & 63;
  const int g = lane >> 4, r16 = lane & 15;
  const int wr = wid >> 2, wc = wid & 3;              // 2M x 4N waves
  const int m0 = blockIdx.x * 256, n0 = blockIdx.y * 256;
  // swizzled k-slot offsets (elements) for ks0/ks1 reads
  const int sw0 = ((g     ) ^ (r16 & 7)) * 8;
  const int sw1 = ((g + 4) ^ (r16 & 7)) * 8;

  const bh_t* Ab = A + (size_t)blockIdx.z * K + (size_t)m0 * lda;
  const bh_t* Bb = B + (size_t)blockIdx.z * K + (size_t)n0 * lda;
  const bh_t* Ab1 = Ab + (size_t)128 * lda;
  const bh_t* Bb1 = Bb + (size_t)128 * lda;
  const int nt = K >> 6;   // = 12

  fx4 acc[8][4] = {};

  // stage one 128x64 half-tile (16 KB): dst linear, SOURCE pre-swizzled with
  // the involution slot ^= row&7 so the ds_read-side XOR lands on the data.
  auto stageHalf = [&](bh_t* dst, const bh_t* src, int t) {
    const int k0 = t << 6;
    #pragma unroll
    for (int j = 0; j < 2; ++j) {
      const int idx = j * 512 + tid;
      const int row = idx >> 3;
      const int slot = (idx & 7) ^ (row & 7);
      gload_lds16(src + (size_t)row * lda + k0 + slot * 8, dst + (size_t)idx * 8);
    }
  };

#define LM_TILE(CA, CB, NA, NB, T)                                            \
  {                                                                           \
    const bh_t* ca = &CA[wr][0][0];                                           \
    const bh_t* cb = &CB[wc >> 1][0][0] + (size_t)((wc & 1) * 64) * 64;       \
    bfx8 a0[4], b0[4], b1[4];                                                 \
    /* ph1: A mi0-3 ks0 + B ks0, 16 MFMA */                                   \
    _Pragma("unroll")                                                         \
    for (int ni = 0; ni < 4; ++ni)                                            \
      b0[ni] = *(const bfx8*)(cb + (size_t)(ni * 16 + r16) * 64 + sw0);       \
    _Pragma("unroll")                                                         \
    for (int mi = 0; mi < 4; ++mi)                                            \
      a0[mi] = *(const bfx8*)(ca + (size_t)(mi * 16 + r16) * 64 + sw0);       \
    __builtin_amdgcn_s_setprio(1);                                            \
    _Pragma("unroll")                                                         \
    for (int mi = 0; mi < 4; ++mi)                                            \
      _Pragma("unroll")                                                       \
      for (int ni = 0; ni < 4; ++ni)                                          \
        acc[mi][ni] = mfma16(a0[mi], b0[ni], acc[mi][ni]);                    \
    __builtin_amdgcn_s_setprio(0);                                            \
    /* ph2: stage (T+1).H1; A mi4-7 ks0 */                                    \
    if ((T) + 1 < nt) stageHalf(&NA[1][0][0], Ab1, (T) + 1);                  \
    _Pragma("unroll")                                                         \
    for (int mi = 0; mi < 4; ++mi)                                            \
      a0[mi] = *(const bfx8*)(ca + (size_t)(64 + mi * 16 + r16) * 64 + sw0);  \
    __builtin_amdgcn_s_setprio(1);                                            \
    _Pragma("unroll")                                                         \
    for (int mi = 0; mi < 4; ++mi)                                            \
      _Pragma("unroll")                                                       \
      for (int ni = 0; ni < 4; ++ni)                                          \
        acc[4 + mi][ni] = mfma16(a0[mi], b0[ni], acc[4 + mi][ni]);            \
    __builtin_amdgcn_s_setprio(0);                                            \
    /* ph3: stage (T+1).H2; A mi0-3 ks1 + B ks1 */                            \
    if ((T) + 1 < nt) stageHalf(&NB[0][0][0], Bb, (T) + 1);                   \
    _Pragma("unroll")                                                         \
    for (int ni = 0; ni < 4; ++ni)                                            \
      b1[ni] = *(const bfx8*)(cb + (size_t)(ni * 16 + r16) * 64 + sw1);       \
    _Pragma("unroll")                                                         \
    for (int mi = 0; mi < 4; ++mi)                                            \
      a0[mi] = *(const bfx8*)(ca + (size_t)(mi * 16 + r16) * 64 + sw1);       \
    __builtin_amdgcn_s_setprio(1);                                            \
    _Pragma("unroll")                                                         \
    for (int mi = 0; mi < 4; ++mi)                                            \
      _Pragma("unroll")                                                       \
      for (int ni = 0; ni < 4; ++ni)                                          \
        acc[mi][ni] = mfma16(a0[mi], b1[ni], acc[mi][ni]);                    \
    __builtin_amdgcn_s_setprio(0);                                            \
    /* ph4: stage (T+1).H3; A mi4-7 ks1 */                                    \
    if ((T) + 1 < nt) stageHalf(&NB[1][0][0], Bb1, (T) + 1);                  \
    _Pragma("unroll")                                                         \
    for (int mi = 0; mi < 4; ++mi)                                            \
      a0[mi] = *(const bfx8*)(ca + (size_t)(64 + mi * 16 + r16) * 64 + sw1);  \
    __builtin_amdgcn_s_setprio(1);                                            \
    _Pragma("unroll")                                                         \
    for (int mi = 0; mi < 4; ++mi)                                            \
      _Pragma("unroll")                                                       \
      for (int ni = 0; ni < 4; ++ni)                                          \
        acc[4 + mi][ni] = mfma16(a0[mi], b1[ni], acc[4 + mi][ni]);            \
    __builtin_amdgcn_s_setprio(0);                                            \
    /* boundary */                                                            \
    asm volatile("s_waitcnt lgkmcnt(0)" ::: "memory");                        \
    __builtin_amdgcn_s_barrier();                                             \
    if ((T) + 2 < nt) {                                                       \
      stageHalf(&CA[0][0][0], Ab, (T) + 2);                                   \
      asm volatile("s_waitcnt vmcnt(2)" ::: "memory");                        \
    } else if ((T) + 1 < nt) {                                                \
      asm volatile("s_waitcnt vmcnt(0)" ::: "memory");                        \
    }                                                                         \
    __builtin_amdgcn_s_barrier();                                             \
    asm volatile("" ::: "memory");                                            \
  }

  // prologue: tile 0 fully + tile 1.H0; 10 loads issued, keep 2 in flight
  stageHalf(&LA0[0][0][0], Ab, 0);
  stageHalf(&LA0[1][0][0], Ab1, 0);
  stageHalf(&LB0[0][0][0], Bb, 0);
  stageHalf(&LB0[1][0][0], Bb1, 0);
  stageHalf(&LA1[0][0][0], Ab, 1);
  asm volatile("s_waitcnt vmcnt(2)" ::: "memory");
  __builtin_amdgcn_s_barrier();
  asm volatile("" ::: "memory");

  for (int t = 0; t < nt; t += 2) {
    LM_TILE(LA0, LB0, LA1, LB1, t);
    LM_TILE(LA1, LB1, LA0, LB0, t + 1);
  }
#undef LM_TILE

  const bool hasBias = flags & 1, doGelu = flags & 4, outBf = flags & 8;
  float* outF = (float*)outp + (size_t)blockIdx.z * ((size_t)M * N);
  bh_t*  outB = (bh_t*)outp;
  #pragma unroll
  for (int mi = 0; mi < 8; ++mi) {
    const int rowb = m0 + wr * 128 + mi * 16 + 4 * g;
    #pragma unroll
    for (int ni = 0; ni < 4; ++ni) {
      const int col = n0 + wc * 64 + ni * 16 + r16;
      if (col >= N) continue;
      const float bv = hasBias ? bias[col] : 0.0f;
      #pragma unroll
      for (int rr = 0; rr < 4; ++rr) {
        const size_t idx = (size_t)(rowb + rr) * N + col;
        float v = acc[mi][ni][rr] + bv;
        if (doGelu) v = 0.5f * v * (1.0f + erff(v * 0.70710678118654752f));
        if (outBf) outB[idx] = (bh_t)v; else outF[idx] = v;
      }
    }
  }
}

// ---------------------------------------------------------------------------
// 128x128 GEMM (R5 3-buffer pipeline) — used for proj (split-K x4).
// flags: 1=bias, 2=residual, 4=gelu, 8=out bf16. K%96==0 (nk%3).
// ---------------------------------------------------------------------------
__global__ __launch_bounds__(256, 3) void gemm_bt(
    const bh_t* __restrict__ A, const bh_t* __restrict__ B,
    const float* __restrict__ bias, const float* __restrict__ resid,
    void* __restrict__ outp, int M, int N, int K, int lda, int flags)
{
  __shared__ bh_t As0[4][128][8], Bs0[4][128][8];
  __shared__ bh_t As1[4][128][8], Bs1[4][128][8];
  __shared__ bh_t As2[4][128][8], Bs2[4][128][8];
  const int tid  = threadIdx.x;
  const int wave = tid >> 6, lane = tid & 63;
  const int g = lane >> 4, r16 = lane & 15;
  const int m0 = blockIdx.x * 128, n0 = blockIdx.y * 128;
  const int wm = (wave >> 1) * 64, wn = (wave & 1) * 64;

  const bh_t* Ab = A;
  const bh_t* Bb = B;
  if (gridDim.z > 1) {
    Ab += (size_t)blockIdx.z * K;
    Bb += (size_t)blockIdx.z * K;
  }
  Ab += (size_t)m0 * lda;
  Bb += (size_t)n0 * lda;

  const int row0 = tid & 127, kb0 = tid >> 7;
  const int kb1 = kb0 + 2;

  fx4 acc[4][4] = {};
  const int nk = K >> 5;

  auto stageTo = [&](bh_t* AsF, bh_t* BsF, int t) {
    const int k0 = t << 5;
    gload_lds16(Ab + (size_t)row0 * lda + k0 + kb0 * 8, AsF + (size_t)(wave * 64) * 8);
    gload_lds16(Ab + (size_t)row0 * lda + k0 + kb1 * 8, AsF + (size_t)(256 + wave * 64) * 8);
    gload_lds16(Bb + (size_t)row0 * lda + k0 + kb0 * 8, BsF + (size_t)(wave * 64) * 8);
    gload_lds16(Bb + (size_t)row0 * lda + k0 + kb1 * 8, BsF + (size_t)(256 + wave * 64) * 8);
  };

#define GPT_PHASE(CURA, CURB, NXA, NXB, T)                                   \
  {                                                                          \
    if ((T) + 1 < nk) { asm volatile("s_waitcnt vmcnt(4)" ::: "memory"); }   \
    else              { asm volatile("s_waitcnt vmcnt(0)" ::: "memory"); }   \
    __builtin_amdgcn_s_barrier();                                            \
    asm volatile("" ::: "memory");                                           \
    if ((T) + 2 < nk) stageTo(&NXA[0][0][0], &NXB[0][0][0], (T) + 2);        \
    bfx8 af[4], bfr[4];                                                      \
    _Pragma("unroll")                                                        \
    for (int mi = 0; mi < 4; ++mi)                                           \
      af[mi] = *(const bfx8*)&CURA[g][wm + mi * 16 + r16][0];                \
    _Pragma("unroll")                                                        \
    for (int ni = 0; ni < 4; ++ni)                                           \
      bfr[ni] = *(const bfx8*)&CURB[g][wn + ni * 16 + r16][0];               \
    _Pragma("unroll")                                                        \
    for (int mi = 0; mi < 4; ++mi)                                           \
      _Pragma("unroll")                                                      \
      for (int ni = 0; ni < 4; ++ni)                                         \
        acc[mi][ni] = mfma16(af[mi], bfr[ni], acc[mi][ni]);                  \
  }

  stageTo(&As0[0][0][0], &Bs0[0][0][0], 0);
  stageTo(&As1[0][0][0], &Bs1[0][0][0], 1);
  for (int t = 0; t < nk; t += 3) {
    GPT_PHASE(As0, Bs0, As2, Bs2, t);
    GPT_PHASE(As1, Bs1, As0, Bs0, t + 1);
    GPT_PHASE(As2, Bs2, As1, Bs1, t + 2);
  }
#undef GPT_PHASE

  const bool hasBias = flags & 1, hasRes = flags & 2;
  const bool doGelu  = flags & 4, outBf  = flags & 8;
  float* outF = (float*)outp + (size_t)blockIdx.z * ((size_t)M * N);
  bh_t*  outB = (bh_t*)outp;
  #pragma unroll
  for (int mi = 0; mi < 4; ++mi) {
    #pragma unroll
    for (int ni = 0; ni < 4; ++ni) {
      const int col = n0 + wn + ni * 16 + r16;
      if (col >= N) continue;
      const int rowb = m0 + wm + mi * 16 + 4 * g;
      const float bv = hasBias ? bias[col] : 0.0f;
      #pragma unroll
      for (int rr = 0; rr < 4; ++rr) {
        const size_t idx = (size_t)(rowb + rr) * N + col;
        float v = acc[mi][ni][rr] + bv;
        if (doGelu) v = 0.5f * v * (1.0f + erff(v * 0.70710678118654752f));
        if (hasRes) v += resid[idx];
        if (outBf) outB[idx] = (bh_t)v; else outF[idx] = v;
      }
    }
  }
}

// ---------------------------------------------------------------------------
// fused split-K reduce + residual + LayerNorm:
//   xnew = x + bias + sum_s part[s];  x <- xnew;  out <- LN(xnew)*w + b (bf16)
// one wave per row (CDIM=768, 12 f32/lane).
// ---------------------------------------------------------------------------
__global__ __launch_bounds__(256) void skred_ln(
    const float* __restrict__ part, const float* __restrict__ bias,
    float* __restrict__ x, const float* __restrict__ w,
    const float* __restrict__ bb, bh_t* __restrict__ out, int S)
{
  const int wave = threadIdx.x >> 6, lane = threadIdx.x & 63;
  const int row = blockIdx.x * 4 + wave;
  const size_t base = (size_t)row * CDIM;
  const int off = lane * 4;
  const size_t stride = (size_t)MROWS * CDIM;

  float4 v0 = *(const float4*)(x + base + off);
  float4 v1 = *(const float4*)(x + base + 256 + off);
  float4 v2 = *(const float4*)(x + base + 512 + off);
  for (int s = 0; s < S; ++s) {
    const float* pr = part + s * stride + base;
    const float4 p0 = *(const float4*)(pr + off);
    const float4 p1 = *(const float4*)(pr + 256 + off);
    const float4 p2 = *(const float4*)(pr + 512 + off);
    v0.x += p0.x; v0.y += p0.y; v0.z += p0.z; v0.w += p0.w;
    v1.x += p1.x; v1.y += p1.y; v1.z += p1.z; v1.w += p1.w;
    v2.x += p2.x; v2.y += p2.y; v2.z += p2.z; v2.w += p2.w;
  }
  const float4 q0 = *(const float4*)(bias + off);
  const float4 q1 = *(const float4*)(bias + 256 + off);
  const float4 q2 = *(const float4*)(bias + 512 + off);
  v0.x += q0.x; v0.y += q0.y; v0.z += q0.z; v0.w += q0.w;
  v1.x += q1.x; v1.y += q1.y; v1.z += q1.z; v1.w += q1.w;
  v2.x += q2.x; v2.y += q2.y; v2.z += q2.z; v2.w += q2.w;
  *(float4*)(x + base + off) = v0;
  *(float4*)(x + base + 256 + off) = v1;
  *(float4*)(x + base + 512 + off) = v2;

  float s1 = v0.x + v0.y + v0.z + v0.w + v1.x + v1.y + v1.z + v1.w
           + v2.x + v2.y + v2.z + v2.w;
  float ss = v0.x*v0.x + v0.y*v0.y + v0.z*v0.z + v0.w*v0.w
           + v1.x*v1.x + v1.y*v1.y + v1.z*v1.z + v1.w*v1.w
           + v2.x*v2.x + v2.y*v2.y + v2.z*v2.z + v2.w*v2.w;
  #pragma unroll
  for (int d = 1; d < 64; d <<= 1) { s1 += __shfl_xor(s1, d); ss += __shfl_xor(ss, d); }
  const float mean = s1 * (1.0f / 768.0f);
  const float inv = rsqrtf(ss * (1.0f / 768.0f) - mean * mean + 1e-5f);
  bh_t* orow = out + base;

  const float4 w0 = *(const float4*)(w + off),       b0 = *(const float4*)(bb + off);
  const float4 w1 = *(const float4*)(w + 256 + off), b1 = *(const float4*)(bb + 256 + off);
  const float4 w2 = *(const float4*)(w + 512 + off), b2 = *(const float4*)(bb + 512 + off);
  bfx4 o;
  o[0] = (bh_t)((v0.x - mean) * inv * w0.x + b0.x);
  o[1] = (bh_t)((v0.y - mean) * inv * w0.y + b0.y);
  o[2] = (bh_t)((v0.z - mean) * inv * w0.z + b0.z);
  o[3] = (bh_t)((v0.w - mean) * inv * w0.w + b0.w);
  *(bfx4*)(orow + off) = o;
  o[0] = (bh_t)((v1.x - mean) * inv * w1.x + b1.x);
  o[1] = (bh_t)((v1.y - mean) * inv * w1.y + b1.y);
  o[2] = (bh_t)((v1.z - mean) * inv * w1.z + b1.z);
  o[3] = (bh_t)((v1.w - mean) * inv * w1.w + b1.w);
  *(bfx4*)(orow + 256 + off) = o;
  o[0] = (bh_t)((v2.x - mean) * inv * w2.x + b2.x);
  o[1] = (bh_t)((v2.y - mean) * inv * w2.y + b2.y);
  o[2] = (bh_t)((v2.z - mean) * inv * w2.z + b2.z);
  o[3] = (bh_t)((v2.w - mean) * inv * w2.w + b2.w);
  *(bfx4*)(orow + 512 + off) = o;
}

// ---------------------------------------------------------------------------
// Flash attention, causal. One wave per (b, h, 16 q-rows).
// ---------------------------------------------------------------------------
__global__ __launch_bounds__(256) void attn_fwd(
    const bh_t* __restrict__ qkv, const bh_t* __restrict__ vT,
    bh_t* __restrict__ outb)
{
  __shared__ bh_t P[4][16][56];
  const int wave = threadIdx.x >> 6, lane = threadIdx.x & 63;
  const int g = lane >> 4, r16 = lane & 15;
  const int gw = blockIdx.x * 4 + wave;
  const int qblk = gw & 63;
  const int bh = gw >> 6;
  const int h = bh % NHEAD, b = bh / NHEAD;
  const int qbase = qblk * 16;
  const int qidx = qbase + r16;

  const bh_t* qp = qkv + (size_t)(b * TSEQ + qbase + r16) * (3 * CDIM) + h * HDIM + 8 * g;
  const bfx8 qf0 = *(const bfx8*)qp;
  const bfx8 qf1 = *(const bfx8*)(qp + 32);

  fx4 o[4] = {};
  float m = -INFINITY, l = 0.0f;
  const int ntiles = qblk / 2 + 1;

  for (int t = 0; t < ntiles; ++t) {
    const int kv0 = t * 32;
    const bh_t* kp = qkv + (size_t)(b * TSEQ + kv0 + r16) * (3 * CDIM) + CDIM + h * HDIM + 8 * g;
    const bfx8 ka0 = *(const bfx8*)kp;
    const bfx8 ka1 = *(const bfx8*)(kp + 32);
    const bfx8 kb0 = *(const bfx8*)(kp + 16 * (3 * CDIM));
    const bfx8 kb1 = *(const bfx8*)(kp + 16 * (3 * CDIM) + 32);
    fx4 s0 = {}, s1 = {};
    s0 = mfma16(ka0, qf0, s0); s0 = mfma16(ka1, qf1, s0);   // S^T: [kv][q]
    s1 = mfma16(kb0, qf0, s1); s1 = mfma16(kb1, qf1, s1);

    float mx = -INFINITY;
    float sv0[4], sv1[4];
    #pragma unroll
    for (int rr = 0; rr < 4; ++rr) {
      const int kva = kv0 + 4 * g + rr;
      const int kvb = kva + 16;
      sv0[rr] = (kva <= qidx) ? s0[rr] * 0.125f : -INFINITY;
      sv1[rr] = (kvb <= qidx) ? s1[rr] * 0.125f : -INFINITY;
      mx = fmaxf(mx, fmaxf(sv0[rr], sv1[rr]));
    }
    mx = fmaxf(mx, __shfl_xor(mx, 16));
    mx = fmaxf(mx, __shfl_xor(mx, 32));
    const float mnew = fmaxf(m, mx);
    const float corr = __expf(m - mnew);

    float ps = 0.0f;
    float pv0[4], pv1[4];
    #pragma unroll
    for (int rr = 0; rr < 4; ++rr) {
      pv0[rr] = __expf(sv0[rr] - mnew);
      pv1[rr] = __expf(sv1[rr] - mnew);
      ps += pv0[rr] + pv1[rr];
    }
    ps += __shfl_xor(ps, 16);
    ps += __shfl_xor(ps, 32);
    l = l * corr + ps;
    m = mnew;

    #pragma unroll
    for (int rr = 0; rr < 4; ++rr) {
      const float cr = __shfl(corr, 4 * g + rr);
      o[0][rr] *= cr; o[1][rr] *= cr; o[2][rr] *= cr; o[3][rr] *= cr;
    }

    bfx4 w0, w1;
    #pragma unroll
    for (int rr = 0; rr < 4; ++rr) { w0[rr] = (bh_t)pv0[rr]; w1[rr] = (bh_t)pv1[rr]; }
    *(bfx4*)&P[wave][r16][4 * g]      = w0;
    *(bfx4*)&P[wave][r16][16 + 4 * g] = w1;
    __builtin_amdgcn_wave_barrier();
    const bfx8 pf = *(const bfx8*)&P[wave][r16][8 * g];

    #pragma unroll
    for (int fi = 0; fi < 4; ++fi) {
      const bh_t* vp = vT + (size_t)(bh * HDIM + fi * 16 + r16) * TSEQ + kv0 + 8 * g;
      const bfx8 vf = *(const bfx8*)vp;
      o[fi] = mfma16(pf, vf, o[fi]);
    }
  }

  #pragma unroll
  for (int rr = 0; rr < 4; ++rr) {
    const float lr = __shfl(l, 4 * g + rr);
    const float inv = 1.0f / lr;
    const int trow = b * TSEQ + qbase + 4 * g + rr;
    #pragma unroll
    for (int fi = 0; fi < 4; ++fi)
      outb[(size_t)trow * CDIM + h * HDIM + fi * 16 + r16] = (bh_t)(o[fi][rr] * inv);
  }
}

// ---------------------------------------------------------------------------
// LayerNorm: f32 in -> bf16 out. One wave per row. (layer 0 entry only)
// ---------------------------------------------------------------------------
__global__ __launch_bounds__(256) void ln_fwd(
    const float* __restrict__ x, const float* __restrict__ w,
    const float* __restrict__ bb, bh_t* __restrict__ out)
{
  const int wave = threadIdx.x >> 6, lane = threadIdx.x & 63;
  const int row = blockIdx.x * 4 + wave;
  const float* xr = x + (size_t)row * CDIM;
  const int off = lane * 4;
  const float4 v0 = *(const float4*)(xr + off);
  const float4 v1 = *(const float4*)(xr + 256 + off);
  const float4 v2 = *(const float4*)(xr + 512 + off);
  float s  = v0.x + v0.y + v0.z + v0.w + v1.x + v1.y + v1.z + v1.w
           + v2.x + v2.y + v2.z + v2.w;
  float ss = v0.x*v0.x + v0.y*v0.y + v0.z*v0.z + v0.w*v0.w
           + v1.x*v1.x + v1.y*v1.y + v1.z*v1.z + v1.w*v1.w
           + v2.x*v2.x + v2.y*v2.y + v2.z*v2.z + v2.w*v2.w;
  #pragma unroll
  for (int d = 1; d < 64; d <<= 1) { s += __shfl_xor(s, d); ss += __shfl_xor(ss, d); }
  const float mean = s * (1.0f / 768.0f);
  const float inv = rsqrtf(ss * (1.0f / 768.0f) - mean * mean + 1e-5f);
  bh_t* orow = out + (size_t)row * CDIM;

  const float4 w0 = *(const float4*)(w + off),  b0 = *(const float4*)(bb + off);
  const float4 w1 = *(const float4*)(w + 256 + off), b1 = *(const float4*)(bb + 256 + off);
  const float4 w2 = *(const float4*)(w + 512 + off), b2 = *(const float4*)(bb + 512 + off);
  bfx4 o;
  o[0] = (bh_t)((v0.x - mean) * inv * w0.x + b0.x);
  o[1] = (bh_t)((v0.y - mean) * inv * w0.y + b0.y);
  o[2] = (bh_t)((v0.z - mean) * inv * w0.z + b0.z);
  o[3] = (bh_t)((v0.w - mean) * inv * w0.w + b0.w);
  *(bfx4*)(orow + off) = o;
  o[0] = (bh_t)((v1.x - mean) * inv * w1.x + b1.x);
  o[1] = (bh_t)((v1.y - mean) * inv * w1.y + b1.y);
  o[2] = (bh_t)((v1.z - mean) * inv * w1.z + b1.z);
  o[3] = (bh_t)((v1.w - mean) * inv * w1.w + b1.w);
  *(bfx4*)(orow + 256 + off) = o;
  o[0] = (bh_t)((v2.x - mean) * inv * w2.x + b2.x);
  o[1] = (bh_t)((v2.y - mean) * inv * w2.y + b2.y);
  o[2] = (bh_t)((v2.z - mean) * inv * w2.z + b2.z);
  o[3] = (bh_t)((v2.w - mean) * inv * w2.w + b2.w);
  *(bfx4*)(orow + 512 + off) = o;
}

// ---------------------------------------------------------------------------
__global__ void embed_k(const int* __restrict__ ids, const float* __restrict__ tok,
                        const float* __restrict__ pos, float* __restrict__ x)
{
  const int bt = blockIdx.x;
  const int t = bt & (TSEQ - 1);
  const int id = ids[bt];
  const float* tr = tok + (size_t)id * CDIM;
  const float* pr = pos + (size_t)t * CDIM;
  float* xr = x + (size_t)bt * CDIM;
  for (int j = threadIdx.x; j < CDIM; j += 256) xr[j] = tr[j] + pr[j];
}

// transpose + f32->bf16: in [L][R][Cn] -> out [L][Cn][R]
__global__ void tconv(const float* __restrict__ in, bh_t* __restrict__ out, int R, int Cn)
{
  __shared__ float tile[32][33];
  const size_t msz = (size_t)R * Cn;
  in  += msz * blockIdx.z;
  out += msz * blockIdx.z;
  const int tx = threadIdx.x & 31, ty = threadIdx.x >> 5;
  const int c0 = blockIdx.x * 32, r0 = blockIdx.y * 32;
  #pragma unroll
  for (int i = 0; i < 32; i += 8)
    tile[ty + i][tx] = in[(size_t)(r0 + ty + i) * Cn + c0 + tx];
  __syncthreads();
  #pragma unroll
  for (int i = 0; i < 32; i += 8)
    out[(size_t)(c0 + ty + i) * R + r0 + tx] = (bh_t)tile[tx][ty + i];
}

// tok_emb f32 [V][C] -> bf16 [VPAD][C], zero-padded rows
__global__ void embconv(const float* __restrict__ in, bh_t* __restrict__ out)
{
  const size_t i4 = ((size_t)blockIdx.x * 256 + threadIdx.x) * 4;
  if (i4 >= (size_t)VPAD * CDIM) return;
  const size_t vlim = (size_t)VOCAB * CDIM;
  float4 f = make_float4(0.f, 0.f, 0.f, 0.f);
  if (i4 < vlim) f = *(const float4*)(in + i4);
  bfx4 o;
  o[0] = (bh_t)f.x; o[1] = (bh_t)f.y; o[2] = (bh_t)f.z; o[3] = (bh_t)f.w;
  *(bfx4*)(out + i4) = o;
}

// V slice of qkv -> vT[bh*64 + d][t]
__global__ void vtrans(const bh_t* __restrict__ qkv, bh_t* __restrict__ vT)
{
  __shared__ bh_t tile[32][34];
  const int bh = blockIdx.z;
  const int b = bh / NHEAD, h = bh % NHEAD;
  const int d0 = blockIdx.x * 32, t0 = blockIdx.y * 32;
  const int tx = threadIdx.x & 31, ty = threadIdx.x >> 5;
  #pragma unroll
  for (int i = 0; i < 32; i += 8)
    tile[ty + i][tx] = qkv[(size_t)(b * TSEQ + t0 + ty + i) * (3 * CDIM) + 2 * CDIM + h * HDIM + d0 + tx];
  __syncthreads();
  #pragma unroll
  for (int i = 0; i < 32; i += 8)
    vT[(size_t)(bh * HDIM + d0 + ty + i) * TSEQ + t0 + tx] = tile[tx][ty + i];
}

// ---------------------------------------------------------------------------
extern "C" void kernel_launch(void* const* d_in, const int* in_sizes, int n_in,
                              void* d_out, int out_size, void* d_ws, size_t ws_size,
                              hipStream_t stream)
{
  (void)in_sizes; (void)n_in; (void)out_size; (void)ws_size;
  const int*   ids    = (const int*)d_in[0];
  const float* tok    = (const float*)d_in[1];
  const float* pos    = (const float*)d_in[2];
  const float* qkv_w  = (const float*)d_in[3];
  const float* qkv_b  = (const float*)d_in[4];
  const float* proj_w = (const float*)d_in[5];
  const float* proj_b = (const float*)d_in[6];
  const float* ln1_w  = (const float*)d_in[7];
  const float* ln1_b  = (const float*)d_in[8];
  const float* ln2_w  = (const float*)d_in[9];
  const float* ln2_b  = (const float*)d_in[10];
  const float* fc1_w  = (const float*)d_in[11];
  const float* fc1_b  = (const float*)d_in[12];
  const float* fc2_w  = (const float*)d_in[13];
  const float* fc2_b  = (const float*)d_in[14];
  const float* lnf_w  = (const float*)d_in[15];
  const float* lnf_b  = (const float*)d_in[16];

  // ---- scratch in ws (activations + embT), ~153 MB
  char* wp = (char*)d_ws;
  auto carve = [&](size_t bytes) { char* p = wp; wp += (bytes + 255) & ~(size_t)255; return p; };
  float* x     = (float*)carve((size_t)MROWS * CDIM * 4);
  bh_t*  hbuf  = (bh_t*)carve((size_t)MROWS * CDIM * 2);
  bh_t*  qkvb  = (bh_t*)carve((size_t)MROWS * 3 * CDIM * 2);
  bh_t*  vT    = (bh_t*)carve((size_t)48 * HDIM * TSEQ * 2);
  bh_t*  attno = (bh_t*)carve((size_t)MROWS * CDIM * 2);
  bh_t*  mlp1  = (bh_t*)carve((size_t)MROWS * 3072 * 2);
  bh_t*  embT  = (bh_t*)carve((size_t)VPAD * CDIM * 2);

  // ---- staged in d_out (dead before lm_head overwrites it), ~270 MB of 823
  char* op = (char*)d_out;
  auto carveO = [&](size_t bytes) { char* p = op; op += (bytes + 255) & ~(size_t)255; return p; };
  bh_t* qkvwT  = (bh_t*)carveO((size_t)NLAYER * 3 * CDIM * CDIM * 2);
  bh_t* projwT = (bh_t*)carveO((size_t)NLAYER * CDIM * CDIM * 2);
  bh_t* fc1wT  = (bh_t*)carveO((size_t)NLAYER * 3072 * CDIM * 2);
  bh_t* fc2wT  = (bh_t*)carveO((size_t)NLAYER * CDIM * 3072 * 2);
  float* skpart = (float*)carveO((size_t)4 * MROWS * CDIM * 4);   // split-K partials

  tconv<<<dim3(2304 / 32, 768 / 32, NLAYER), 256, 0, stream>>>(qkv_w, qkvwT, 768, 2304);
  tconv<<<dim3(768 / 32, 768 / 32, NLAYER), 256, 0, stream>>>(proj_w, projwT, 768, 768);
  tconv<<<dim3(3072 / 32, 768 / 32, NLAYER), 256, 0, stream>>>(fc1_w, fc1wT, 768, 3072);
  tconv<<<dim3(768 / 32, 3072 / 32, NLAYER), 256, 0, stream>>>(fc2_w, fc2wT, 3072, 768);
  embconv<<<((VPAD * CDIM / 4) + 255) / 256, 256, 0, stream>>>(tok, embT);
  embed_k<<<MROWS, 256, 0, stream>>>(ids, tok, pos, x);

  ln_fwd<<<MROWS / 4, 256, 0, stream>>>(x, ln1_w, ln1_b, hbuf);
  for (int l = 0; l < NLAYER; ++l) {
    // qkv: 256^2, grid 16x9
    gemm256<<<dim3(16, 9), 512, 0, stream>>>(hbuf, qkvwT + (size_t)l * 3 * CDIM * CDIM,
        qkv_b + l * 3 * CDIM, qkvb, MROWS, 3 * CDIM, CDIM, CDIM, 1 | 8);
    vtrans<<<dim3(2, 32, 48), 256, 0, stream>>>(qkvb, vT);
    attn_fwd<<<768, 256, 0, stream>>>(qkvb, vT, attno);
    // proj: 128^2 split-K x4 (K_eff=192, nk=6), 768 blocks
    gemm_bt<<<dim3(32, 6, 4), 256, 0, stream>>>(attno,
        projwT + (size_t)l * CDIM * CDIM, nullptr, nullptr,
        skpart, MROWS, CDIM, 192, CDIM, 0);
    skred_ln<<<MROWS / 4, 256, 0, stream>>>(skpart, proj_b + l * CDIM, x,
        ln2_w + l * CDIM, ln2_b + l * CDIM, hbuf, 4);
    // fc1: 256^2, grid 16x12
    gemm256<<<dim3(16, 12), 512, 0, stream>>>(hbuf, fc1wT + (size_t)l * 3072 * CDIM,
        fc1_b + l * 3072, mlp1, MROWS, 3072, CDIM, CDIM, 1 | 4 | 8);
    // fc2: 256^2 split-K x4 (K_eff=768, nt=12), grid 16x3x4
    gemm256<<<dim3(16, 3, 4), 512, 0, stream>>>(mlp1, fc2wT + (size_t)l * CDIM * 3072,
        nullptr, skpart, MROWS, CDIM, 768, 3072, 0);
    const float* nw = (l + 1 < NLAYER) ? ln1_w + (l + 1) * CDIM : lnf_w;
    const float* nb = (l + 1 < NLAYER) ? ln1_b + (l + 1) * CDIM : lnf_b;
    skred_ln<<<MROWS / 4, 256, 0, stream>>>(skpart, fc2_b + l * CDIM, x, nw, nb, hbuf, 4);
  }
  gemm256<<<dim3(16, VPAD / 256), 512, 0, stream>>>(hbuf, embT, nullptr,
      (float*)d_out, MROWS, VOCAB, CDIM, CDIM, 0);
}